// Round 6
// baseline (174.797 us; speedup 1.0000x reference)
//
#include <hip/hip_runtime.h>

typedef __attribute__((ext_vector_type(8))) short short8;
typedef __attribute__((ext_vector_type(4))) float f32x4;

#define SGC (-1.44269504088896341f)   /* -log2(e): sigmoid prescale */
#define THC ( 2.88539008177792681f)   /* 2*log2(e): tanh prescale   */

__device__ __forceinline__ unsigned short f2bf(float f){
  unsigned u = __float_as_uint(f);
  return (unsigned short)((u + 0x7fffu + ((u >> 16) & 1u)) >> 16);
}
__device__ __forceinline__ float bf2f(unsigned short b){
  return __uint_as_float(((unsigned)b) << 16);
}
// single f32 -> bf16 (RNE) in one VALU op; low 16 bits of result are valid
__device__ __forceinline__ unsigned f2bf_cvt(float f){
  unsigned r;
  asm("v_cvt_pk_bf16_f32 %0, %1, %1" : "=v"(r) : "v"(f));
  return r;
}

// ---------------- weight conversion: fp32 -> bf16 in ws ----------------
// wgt layout (u16 elems):
//   whhT_b [384*128]  @0        (PRESCALED: rows<256 *SGC, rows>=256 *THC)
//   W1b    [128*96]   @49152    (96 = 68 padded, zeros)
//   W2b    [128*128]  @61440
//   Wf1b   [256*1152] @77824
//   Wf2b   [128*256]  @372736
//   Wf3b   [64*128]   @405504
//   whhN_b [192*64]   @413696   (PRESCALED: rows<128 *SGC, rows>=128 *THC)
__global__ __launch_bounds__(256) void k_prep(
    const float* __restrict__ Whh_t, const float* __restrict__ W1,
    const float* __restrict__ W2,    const float* __restrict__ Wf1,
    const float* __restrict__ Wf2,   const float* __restrict__ Wf3,
    const float* __restrict__ Whh_n,
    unsigned short* __restrict__ wgt)
{
  int i = blockIdx.x * 256 + threadIdx.x;
  if (i < 49152){
    int g = i >> 7;
    float s = (g < 256) ? SGC : THC;
    wgt[i] = f2bf(Whh_t[i] * s); return;
  }
  i -= 49152;
  if (i < 12288){ int r = i / 96, c = i % 96;
    wgt[49152 + i] = (c < 68) ? f2bf(W1[r*68 + c]) : (unsigned short)0; return; }
  i -= 12288;
  if (i < 16384){ wgt[61440 + i] = f2bf(W2[i]); return; }
  i -= 16384;
  if (i < 294912){ wgt[77824 + i] = f2bf(Wf1[i]); return; }
  i -= 294912;
  if (i < 32768){ wgt[372736 + i] = f2bf(Wf2[i]); return; }
  i -= 32768;
  if (i < 8192){ wgt[405504 + i] = f2bf(Wf3[i]); return; }
  i -= 8192;
  if (i < 12288){
    int g = i >> 6;
    float s = (g < 128) ? SGC : THC;
    wgt[413696 + i] = f2bf(Whh_n[i] * s); return;
  }
}

// ---------------- neighbor GRU + sector pooling ----------------
// 1024 blocks x 512 threads; block handles 2 batches (bi = tid>>8).
// LDS diet: whh [192][72] shared (27648) + per-batch 13312:
//   hall 4x[16][72] (9216) | xst [16][64] f32 transposed (4096).
// Pooling scratch ALIASES xst rows 0..9 (dead after the GRU loop):
//   row0 dist | row1 vx | row2 vy | row3 wv | row4 sid | rows5..9 sect.
// Total 54272 B -> 3 blocks/CU (24 waves/CU).
__global__ __launch_bounds__(512, 6) void k_gru_n(
    const float* __restrict__ ttraj, const float* __restrict__ ntraj,
    const float* __restrict__ rang,  const float* __restrict__ nmask,
    const float* __restrict__ Wih_n,
    const float* __restrict__ bih_n, const float* __restrict__ bhh_n,
    const unsigned short* __restrict__ wgt,
    unsigned short* __restrict__ sf)             // [16384][96] bf16
{
  __shared__ char smem[54272];
  const int tid = threadIdx.x;
  const int bi = tid >> 8, lt = tid & 255;
  const int w = lt >> 6, u = (lt >> 4) & 3, c = lt & 15;
  const int b = blockIdx.x * 2 + bi;
  const unsigned short* whhN_b = wgt + 413696;   // [192][64] prescaled

  unsigned short* whh  = (unsigned short*)smem;                 // [192][72]
  char* pb = smem + 27648 + bi * 13312;
  unsigned short* hall = (unsigned short*)pb;                   // 4 x [16][72]
  unsigned short* hb   = hall + w * 1152;
  float* xst  = (float*)(pb + 9216);                            // [16][64] transposed

  for (int i = tid; i < 1536; i += 512){
    int r = i >> 3, cg = (i & 7) * 8;
    *(short8*)&whh[r*72 + cg] = *(const short8*)&whhN_b[r*64 + cg];
  }
  {
    float4 v = ((const float4*)(ntraj + (size_t)b * 1024))[lt];
    int row = lt >> 2, p4 = (lt & 3) * 4;
    xst[(p4+0)*64 + row] = v.x;
    xst[(p4+1)*64 + row] = v.y;
    xst[(p4+2)*64 + row] = v.z;
    xst[(p4+3)*64 + row] = v.w;
  }
  __syncthreads();

  // per-lane gate constants, prescaled (gate col g = gt*16 + c)
  float wr0[4],wr1[4],br_[4],wz0[4],wz1[4],bz_[4],wn0[4],wn1[4],bi_[4],bh_[4];
#pragma unroll
  for (int gt = 0; gt < 4; ++gt){
    int g = gt*16 + c;
    wr0[gt]=Wih_n[g*2]*SGC;  wr1[gt]=Wih_n[g*2+1]*SGC;  br_[gt]=(bih_n[g]+bhh_n[g])*SGC;
    int gz = 64+g;  wz0[gt]=Wih_n[gz*2]*SGC; wz1[gt]=Wih_n[gz*2+1]*SGC; bz_[gt]=(bih_n[gz]+bhh_n[gz])*SGC;
    int gn = 128+g; wn0[gt]=Wih_n[gn*2]*THC; wn1[gt]=Wih_n[gn*2+1]*THC; bi_[gt]=bih_n[gn]*THC; bh_[gt]=bhh_n[gn]*THC;
  }
  float hcur[4][4];
#pragma unroll
  for (int gt=0; gt<4; ++gt)
#pragma unroll
    for (int q=0; q<4; ++q) hcur[gt][q] = 0.0f;

  float xq0[4], xq1[4];
  auto gates = [&](int gt, const f32x4& aR, const f32x4& aZ, const f32x4& aN){
#pragma unroll
    for (int q = 0; q < 4; ++q){
      float x0 = xq0[q], x1 = xq1[q];
      float rp = __builtin_fmaf(wr0[gt], x0, __builtin_fmaf(wr1[gt], x1, aR[q] + br_[gt]));
      float zp = __builtin_fmaf(wz0[gt], x0, __builtin_fmaf(wz1[gt], x1, aZ[q] + bz_[gt]));
      float r = __builtin_amdgcn_rcpf(1.0f + __builtin_amdgcn_exp2f(rp));
      float z = __builtin_amdgcn_rcpf(1.0f + __builtin_amdgcn_exp2f(zp));
      float hnv = aN[q] + bh_[gt];
      float pn = __builtin_fmaf(wn0[gt], x0, __builtin_fmaf(wn1[gt], x1, __builtin_fmaf(r, hnv, bi_[gt])));
      float E = __builtin_amdgcn_exp2f(pn);
      float n = __builtin_fmaf(-2.0f, __builtin_amdgcn_rcpf(E + 1.0f), 1.0f);
      float hnew = __builtin_fmaf(z, hcur[gt][q] - n, n);
      hcur[gt][q] = hnew;
      hb[(u*4+q)*72 + gt*16 + c] = (unsigned short)f2bf_cvt(hnew);
    }
  };

  for (int st = 0; st < 8; ++st){
#pragma unroll
    for (int q=0; q<4; ++q){
      int sq = w*16 + u*4 + q;
      xq0[q] = xst[st*128 + sq];
      xq1[q] = xst[st*128 + 64 + sq];
    }
    if (st > 0){
      short8 a0 = *(short8*)&hb[c*72 + u*8];
      short8 a1 = *(short8*)&hb[c*72 + 32 + u*8];
      f32x4 zz = {0.f,0.f,0.f,0.f};
#pragma unroll
      for (int gt = 0; gt < 4; ++gt){
        const unsigned short* pr = &whh[(gt*16+c)*72 + u*8];
        const unsigned short* pz = &whh[((4+gt)*16+c)*72 + u*8];
        const unsigned short* pq = &whh[((8+gt)*16+c)*72 + u*8];
        f32x4 aR = __builtin_amdgcn_mfma_f32_16x16x32_bf16(a0, *(const short8*)pr, zz, 0,0,0);
        aR = __builtin_amdgcn_mfma_f32_16x16x32_bf16(a1, *(const short8*)(pr+32), aR, 0,0,0);
        f32x4 aZ = __builtin_amdgcn_mfma_f32_16x16x32_bf16(a0, *(const short8*)pz, zz, 0,0,0);
        aZ = __builtin_amdgcn_mfma_f32_16x16x32_bf16(a1, *(const short8*)(pz+32), aZ, 0,0,0);
        f32x4 aN = __builtin_amdgcn_mfma_f32_16x16x32_bf16(a0, *(const short8*)pq, zz, 0,0,0);
        aN = __builtin_amdgcn_mfma_f32_16x16x32_bf16(a1, *(const short8*)(pq+32), aN, 0,0,0);
        gates(gt, aR, aZ, aN);
      }
    } else {
      f32x4 zz = {0.f,0.f,0.f,0.f};
#pragma unroll
      for (int gt = 0; gt < 4; ++gt) gates(gt, zz, zz, zz);
    }
  }
  __syncthreads();

  // ---- sector pooling (scratch aliased into xst rows 0..9) ----
  if (lt < 64){
    int n = lt;
    float m   = nmask[(size_t)b*64 + n];
    float ang = rang[(size_t)b*64 + n];
    float tx = ttraj[(size_t)b*16 + 14], ty = ttraj[(size_t)b*16 + 15];
    float px = xst[14*64+n], py = xst[15*64+n];
    float vx = px - xst[12*64+n], vy = py - xst[13*64+n];
    float dx = px - tx, dy = py - ty;
    float dist = __builtin_amdgcn_sqrtf(dx*dx + dy*dy);
    int sid = (int)(ang / 0.78539816339744830962f);
    sid = sid < 0 ? 0 : (sid > 7 ? 7 : sid);
    bool valid = m > 0.0f;
    float wv = valid ? __builtin_amdgcn_exp2f(dist * -0.14426950408889634f) : 0.0f;
    xst[0*64+n] = valid ? dist : 0.0f;
    xst[1*64+n] = valid ? vx   : 0.0f;
    xst[2*64+n] = valid ? vy   : 0.0f;
    xst[3*64+n] = wv;
    xst[4*64+n] = valid ? (float)sid : -1.0f;
  }
  __syncthreads();
  if (lt < 8){
    int s = lt;
    float cnt=0.f, sd=0.f, sx=0.f, sy=0.f, sw=0.f;
    for (int n=0; n<64; ++n){
      if (xst[4*64+n] == (float)s){
        cnt += 1.f; sd += xst[n]; sx += xst[64+n]; sy += xst[128+n]; sw += xst[192+n];
      }
    }
    float inv = (cnt > 0.f) ? __builtin_amdgcn_rcpf(cnt) : 0.f;
    xst[5*64+s] = cnt;
    xst[6*64+s] = sd * inv;
    xst[7*64+s] = sx * inv;
    xst[8*64+s] = sy * inv;
    xst[9*64+s] = __builtin_amdgcn_rcpf(sw + 1e-8f);
  }
  __syncthreads();
#pragma unroll
  for (int rep = 0; rep < 2; ++rep){
    int p = lt + rep*256;
    int s = p >> 6, h = p & 63;
    float fs = (float)s;
    float a = 0.f;
    for (int n = 0; n < 64; ++n){
      float wmv = (xst[4*64+n] == fs) ? xst[3*64+n] : 0.f;
      float nf  = bf2f(hall[(n>>4)*1152 + (n&15)*72 + h]);
      a += wmv * nf;
    }
    sf[((size_t)b*8 + s)*96 + 4 + h] = (unsigned short)f2bf_cvt(a * xst[9*64+s]);
  }
  if (lt < 32){
    int s = lt >> 2, cc = lt & 3;
    sf[((size_t)b*8 + s)*96 + cc] = (unsigned short)f2bf_cvt(xst[(5+cc)*64 + s]);
  }
  if (lt < 224){
    int s = lt / 28, cc = 68 + lt % 28;
    sf[((size_t)b*8 + s)*96 + cc] = 0;
  }
}

// ---------------- target GRU: 128 blocks x 256 thr (4 waves) ----------------
// Wave w owns hidden slice [w*32, w*32+32); B-frags register-resident.
// whhT_b is PRESCALED (r,z rows *SGC; n rows *THC).
__global__ __launch_bounds__(256) void k_gru_t(
    const float* __restrict__ ttraj,
    const float* __restrict__ Wih_t, const float* __restrict__ bih_t, const float* __restrict__ bhh_t,
    const unsigned short* __restrict__ wgt,      // whhT_b [384][128] @0
    unsigned short* __restrict__ combined)       // [2048][1152] bf16
{
  __shared__ char smem[9728];
  const int tid = threadIdx.x, w = tid >> 6, u = (tid >> 4) & 3, c = tid & 15;
  unsigned short* hb0 = (unsigned short*)smem;             // [16][136]
  unsigned short* hb1 = (unsigned short*)(smem + 4352);    // [16][136]
  float* xs = (float*)(smem + 8704);                       // [16][16]

  xs[tid] = ttraj[(size_t)blockIdx.x*256 + tid];

  int ntg[6];
  ntg[0] = 2*w; ntg[1] = 2*w+1;
  ntg[2] = 8+2*w; ntg[3] = 9+2*w;
  ntg[4] = 16+2*w; ntg[5] = 17+2*w;

  short8 Bf[6][4];
#pragma unroll
  for (int lt2 = 0; lt2 < 6; ++lt2){
    const unsigned short* wp = wgt + (ntg[lt2]*16 + c)*128 + u*8;
#pragma unroll
    for (int kk = 0; kk < 4; ++kk)
      Bf[lt2][kk] = *(const short8*)(wp + kk*32);
  }

  float Wr0[2],Wr1[2],BR[2],Wz0[2],Wz1[2],BZ[2],Wn0[2],Wn1[2],BI[2],BH[2];
#pragma unroll
  for (int gt = 0; gt < 2; ++gt){
    int g = w*32 + gt*16 + c;
    Wr0[gt]=Wih_t[g*2]*SGC;        Wr1[gt]=Wih_t[g*2+1]*SGC;        BR[gt]=(bih_t[g]+bhh_t[g])*SGC;
    Wz0[gt]=Wih_t[(128+g)*2]*SGC;  Wz1[gt]=Wih_t[(128+g)*2+1]*SGC;  BZ[gt]=(bih_t[128+g]+bhh_t[128+g])*SGC;
    Wn0[gt]=Wih_t[(256+g)*2]*THC;  Wn1[gt]=Wih_t[(256+g)*2+1]*THC;  BI[gt]=bih_t[256+g]*THC; BH[gt]=bhh_t[256+g]*THC;
  }
  float hcur[2][4];
#pragma unroll
  for (int gt=0; gt<2; ++gt)
#pragma unroll
    for (int q=0; q<4; ++q) hcur[gt][q] = 0.0f;
  __syncthreads();

  for (int st = 0; st < 8; ++st){
    unsigned short* rbuf = (st & 1) ? hb0 : hb1;
    unsigned short* wbuf = (st & 1) ? hb1 : hb0;
    f32x4 acc[6];
    if (st > 0){
      short8 a0 = *(short8*)&rbuf[c*136 + u*8];
      short8 a1 = *(short8*)&rbuf[c*136 + 32 + u*8];
      short8 a2 = *(short8*)&rbuf[c*136 + 64 + u*8];
      short8 a3 = *(short8*)&rbuf[c*136 + 96 + u*8];
#pragma unroll
      for (int lt2 = 0; lt2 < 6; ++lt2){
        f32x4 t = {0.f,0.f,0.f,0.f};
        t = __builtin_amdgcn_mfma_f32_16x16x32_bf16(a0, Bf[lt2][0], t, 0,0,0);
        t = __builtin_amdgcn_mfma_f32_16x16x32_bf16(a1, Bf[lt2][1], t, 0,0,0);
        t = __builtin_amdgcn_mfma_f32_16x16x32_bf16(a2, Bf[lt2][2], t, 0,0,0);
        acc[lt2] = __builtin_amdgcn_mfma_f32_16x16x32_bf16(a3, Bf[lt2][3], t, 0,0,0);
      }
    } else {
#pragma unroll
      for (int lt2 = 0; lt2 < 6; ++lt2) acc[lt2] = (f32x4){0.f,0.f,0.f,0.f};
    }
#pragma unroll
    for (int gt = 0; gt < 2; ++gt){
#pragma unroll
      for (int q = 0; q < 4; ++q){
        int sq = u*4 + q;
        float x0 = xs[sq*16 + st*2], x1 = xs[sq*16 + st*2 + 1];
        float rp = __builtin_fmaf(Wr0[gt], x0, __builtin_fmaf(Wr1[gt], x1, acc[gt][q] + BR[gt]));
        float zp = __builtin_fmaf(Wz0[gt], x0, __builtin_fmaf(Wz1[gt], x1, acc[2+gt][q] + BZ[gt]));
        float r = __builtin_amdgcn_rcpf(1.0f + __builtin_amdgcn_exp2f(rp));
        float z = __builtin_amdgcn_rcpf(1.0f + __builtin_amdgcn_exp2f(zp));
        float hnv = acc[4+gt][q] + BH[gt];
        float pn = __builtin_fmaf(Wn0[gt], x0, __builtin_fmaf(Wn1[gt], x1, __builtin_fmaf(r, hnv, BI[gt])));
        float E = __builtin_amdgcn_exp2f(pn);
        float n = __builtin_fmaf(-2.0f, __builtin_amdgcn_rcpf(E + 1.0f), 1.0f);
        float hnew = __builtin_fmaf(z, hcur[gt][q] - n, n);
        hcur[gt][q] = hnew;
        if (st < 7){
          wbuf[sq*136 + w*32 + gt*16 + c] = (unsigned short)f2bf_cvt(hnew);
        } else {
          int row = blockIdx.x*16 + sq;
          combined[(size_t)row*1152 + w*32 + gt*16 + c] = (unsigned short)f2bf_cvt(hnew);
        }
      }
    }
    if (st < 7) __syncthreads();
  }
}

// ---------------- MLP1/MLP2 over (b,s) rows: sf -> enc part of combined ----------------
__global__ __launch_bounds__(256) void k_mlp12(
    const unsigned short* __restrict__ sf,    // [16384][96]
    const unsigned short* __restrict__ wgt,
    const float* __restrict__ b1, const float* __restrict__ b2,
    unsigned short* __restrict__ combined)
{
  __shared__ char smem[18432];
  unsigned short* hb = (unsigned short*)smem + (threadIdx.x >> 6) * 2176;  // [16][136]/wave
  float* b1s = (float*)(smem + 17408);
  float* b2s = b1s + 128;
  const unsigned short* w1b = wgt + 49152;
  const unsigned short* w2b = wgt + 61440;
  const int tid = threadIdx.x, w = tid >> 6, u = (tid >> 4) & 3, c = tid & 15;
  if (tid < 128){ b1s[tid] = b1[tid]; b2s[tid] = b2[tid]; }
  __syncthreads();
  const int rowb = blockIdx.x * 64 + w * 16;

  f32x4 acc[8];
#pragma unroll
  for (int nt=0; nt<8; ++nt) acc[nt] = (f32x4){0.f,0.f,0.f,0.f};
#pragma unroll
  for (int kc=0; kc<3; ++kc){
    short8 a = *(const short8*)&sf[(size_t)(rowb + c)*96 + kc*32 + u*8];
#pragma unroll
    for (int nt=0; nt<8; ++nt){
      short8 bb = *(const short8*)&w1b[(nt*16+c)*96 + kc*32 + u*8];
      acc[nt] = __builtin_amdgcn_mfma_f32_16x16x32_bf16(a, bb, acc[nt], 0,0,0);
    }
  }
#pragma unroll
  for (int nt=0; nt<8; ++nt){
    float bias = b1s[nt*16+c];
#pragma unroll
    for (int q=0; q<4; ++q){
      float v = acc[nt][q] + bias; v = v > 0.f ? v : 0.f;
      hb[(u*4+q)*136 + nt*16 + c] = (unsigned short)f2bf_cvt(v);
    }
  }
  f32x4 acc2[8];
#pragma unroll
  for (int nt=0; nt<8; ++nt) acc2[nt] = (f32x4){0.f,0.f,0.f,0.f};
#pragma unroll
  for (int kc=0; kc<4; ++kc){
    short8 a = *(short8*)&hb[c*136 + kc*32 + u*8];
#pragma unroll
    for (int nt=0; nt<8; ++nt){
      short8 bb = *(const short8*)&w2b[(nt*16+c)*128 + kc*32 + u*8];
      acc2[nt] = __builtin_amdgcn_mfma_f32_16x16x32_bf16(a, bb, acc2[nt], 0,0,0);
    }
  }
#pragma unroll
  for (int nt=0; nt<8; ++nt){
    float bias = b2s[nt*16+c];
#pragma unroll
    for (int q=0; q<4; ++q){
      float v = acc2[nt][q] + bias; v = v > 0.f ? v : 0.f;
      int r = rowb + u*4 + q;
      combined[(size_t)(r >> 3)*1152 + 128 + (r & 7)*128 + nt*16 + c] = (unsigned short)f2bf_cvt(v);
    }
  }
}

// ---------------- head v2: 128 blocks x 256 thr (4 waves) ----------------
__global__ __launch_bounds__(256) void k_head(
    const unsigned short* __restrict__ combined,
    const unsigned short* __restrict__ wgt,
    const float* __restrict__ bf1, const float* __restrict__ bf2, const float* __restrict__ bf3,
    const float* __restrict__ lng, const float* __restrict__ lnb,
    float* __restrict__ out)
{
  __shared__ char smem[15104];
  const int tid = threadIdx.x, w = tid >> 6, u = (tid >> 4) & 3, c = tid & 15;
  unsigned short* f1b = (unsigned short*)smem;                 // [16][264]
  unsigned short* f2b = (unsigned short*)(smem + 8448);        // [16][136]
  float* bf1s = (float*)(smem + 12800); float* bf2s = (float*)(smem + 13824);
  float* bf3s = (float*)(smem + 14336);
  float* lngs = (float*)(smem + 14592); float* lnbs = (float*)(smem + 14848);
  const unsigned short* wf1b = wgt + 77824;
  const unsigned short* wf2b = wgt + 372736;
  const unsigned short* wf3b = wgt + 405504;
  bf1s[tid] = bf1[tid];
  if (tid < 128) bf2s[tid] = bf2[tid];
  if (tid < 64){ bf3s[tid] = bf3[tid]; lngs[tid] = lng[tid]; lnbs[tid] = lnb[tid]; }
  __syncthreads();
  const int rowb = blockIdx.x * 16;

  f32x4 acc[4];
#pragma unroll
  for (int i=0; i<4; ++i) acc[i] = (f32x4){0.f,0.f,0.f,0.f};
#pragma unroll 4
  for (int kc=0; kc<36; ++kc){
    short8 a = *(const short8*)&combined[(size_t)(rowb + c)*1152 + kc*32 + u*8];
#pragma unroll
    for (int i=0; i<4; ++i){
      int nt = w*4 + i;
      short8 bb = *(const short8*)&wf1b[(size_t)(nt*16+c)*1152 + kc*32 + u*8];
      acc[i] = __builtin_amdgcn_mfma_f32_16x16x32_bf16(a, bb, acc[i], 0,0,0);
    }
  }
#pragma unroll
  for (int i=0; i<4; ++i){
    int nt = w*4 + i;
    float bias = bf1s[nt*16+c];
#pragma unroll
    for (int q=0; q<4; ++q){
      float v = acc[i][q] + bias; v = v > 0.f ? v : 0.f;
      f1b[(u*4+q)*264 + nt*16 + c] = (unsigned short)f2bf_cvt(v);
    }
  }
  __syncthreads();

  f32x4 acc2[2];
#pragma unroll
  for (int i=0; i<2; ++i) acc2[i] = (f32x4){0.f,0.f,0.f,0.f};
#pragma unroll
  for (int kc=0; kc<8; ++kc){
    short8 a = *(short8*)&f1b[c*264 + kc*32 + u*8];
#pragma unroll
    for (int i=0; i<2; ++i){
      int nt = w*2 + i;
      short8 bb = *(const short8*)&wf2b[(nt*16+c)*256 + kc*32 + u*8];
      acc2[i] = __builtin_amdgcn_mfma_f32_16x16x32_bf16(a, bb, acc2[i], 0,0,0);
    }
  }
#pragma unroll
  for (int i=0; i<2; ++i){
    int nt = w*2 + i;
    float bias = bf2s[nt*16+c];
#pragma unroll
    for (int q=0; q<4; ++q){
      float v = acc2[i][q] + bias; v = v > 0.f ? v : 0.f;
      f2b[(u*4+q)*136 + nt*16 + c] = (unsigned short)f2bf_cvt(v);
    }
  }
  __syncthreads();

  f32x4 acc3[4];
#pragma unroll
  for (int nt=0; nt<4; ++nt) acc3[nt] = (f32x4){0.f,0.f,0.f,0.f};
#pragma unroll
  for (int kc=0; kc<4; ++kc){
    short8 a = *(short8*)&f2b[c*136 + kc*32 + u*8];
#pragma unroll
    for (int nt=0; nt<4; ++nt){
      short8 bb = *(const short8*)&wf3b[(nt*16+c)*128 + kc*32 + u*8];
      acc3[nt] = __builtin_amdgcn_mfma_f32_16x16x32_bf16(a, bb, acc3[nt], 0,0,0);
    }
  }
  if (w == 0){
    float v[4][4];
#pragma unroll
    for (int nt=0; nt<4; ++nt){
      float bias = bf3s[nt*16+c];
#pragma unroll
      for (int q=0; q<4; ++q){
        float t = acc3[nt][q] + bias; v[nt][q] = t > 0.f ? t : 0.f;
      }
    }
#pragma unroll
    for (int q=0; q<4; ++q){
      float p = v[0][q] + v[1][q] + v[2][q] + v[3][q];
      p += __shfl_xor(p, 1); p += __shfl_xor(p, 2); p += __shfl_xor(p, 4); p += __shfl_xor(p, 8);
      float mu = p * 0.015625f;
      float d0 = v[0][q]-mu, d1 = v[1][q]-mu, d2 = v[2][q]-mu, d3 = v[3][q]-mu;
      float p2 = d0*d0 + d1*d1 + d2*d2 + d3*d3;
      p2 += __shfl_xor(p2, 1); p2 += __shfl_xor(p2, 2); p2 += __shfl_xor(p2, 4); p2 += __shfl_xor(p2, 8);
      float rstd = __builtin_amdgcn_rsqf(p2 * 0.015625f + 1e-5f);
      int row = rowb + u*4 + q;
#pragma unroll
      for (int nt=0; nt<4; ++nt){
        int col = nt*16 + c;
        out[(size_t)row*64 + col] = (v[nt][q] - mu) * rstd * lngs[col] + lnbs[col];
      }
    }
  }
}

extern "C" void kernel_launch(void* const* d_in, const int* in_sizes, int n_in,
                              void* d_out, int out_size, void* d_ws, size_t ws_size,
                              hipStream_t stream)
{
  const float* ttraj = (const float*)d_in[0];
  const float* ntraj = (const float*)d_in[1];
  const float* rang  = (const float*)d_in[2];
  const float* nmask = (const float*)d_in[3];
  const float* Wih_t = (const float*)d_in[4];
  const float* Whh_t = (const float*)d_in[5];
  const float* bih_t = (const float*)d_in[6];
  const float* bhh_t = (const float*)d_in[7];
  const float* Wih_n = (const float*)d_in[8];
  const float* Whh_n = (const float*)d_in[9];
  const float* bih_n = (const float*)d_in[10];
  const float* bhh_n = (const float*)d_in[11];
  const float* W1  = (const float*)d_in[12];
  const float* b1  = (const float*)d_in[13];
  const float* W2  = (const float*)d_in[14];
  const float* b2  = (const float*)d_in[15];
  const float* Wf1 = (const float*)d_in[16];
  const float* bf1 = (const float*)d_in[17];
  const float* Wf2 = (const float*)d_in[18];
  const float* bf2 = (const float*)d_in[19];
  const float* Wf3 = (const float*)d_in[20];
  const float* bf3 = (const float*)d_in[21];
  const float* lng = (const float*)d_in[22];
  const float* lnb = (const float*)d_in[23];

  char* ws = (char*)d_ws;
  unsigned short* combined = (unsigned short*)ws;                  // [2048][1152] bf16
  unsigned short* sf       = (unsigned short*)(ws + 5242880);      // [16384][96] bf16
  unsigned short* wgt      = (unsigned short*)(ws + 8388608);      // bf16 weights

  hipLaunchKernelGGL(k_prep, dim3(1664), dim3(256), 0, stream,
                     Whh_t, W1, W2, Wf1, Wf2, Wf3, Whh_n, wgt);
  hipLaunchKernelGGL(k_gru_n, dim3(1024), dim3(512), 0, stream,
                     ttraj, ntraj, rang, nmask, Wih_n, bih_n, bhh_n, wgt, sf);
  hipLaunchKernelGGL(k_gru_t, dim3(128), dim3(256), 0, stream,
                     ttraj, Wih_t, bih_t, bhh_t, wgt, combined);
  hipLaunchKernelGGL(k_mlp12, dim3(256), dim3(256), 0, stream, sf, wgt, b1, b2, combined);
  hipLaunchKernelGGL(k_head, dim3(128), dim3(256), 0, stream,
                     combined, wgt, bf1, bf2, bf3, lng, lnb, (float*)d_out);
}

// Round 7
// 142.919 us; speedup vs baseline: 1.2230x; 1.2230x over previous
//
#include <hip/hip_runtime.h>

typedef __attribute__((ext_vector_type(8))) short short8;
typedef __attribute__((ext_vector_type(4))) float f32x4;

#define SGC (-1.44269504088896341f)   /* -log2(e): sigmoid prescale */
#define THC ( 2.88539008177792681f)   /* 2*log2(e): tanh prescale   */

__device__ __forceinline__ unsigned short f2bf(float f){
  unsigned u = __float_as_uint(f);
  return (unsigned short)((u + 0x7fffu + ((u >> 16) & 1u)) >> 16);
}
__device__ __forceinline__ float bf2f(unsigned short b){
  return __uint_as_float(((unsigned)b) << 16);
}
// single f32 -> bf16 (RNE) in one VALU op; low 16 bits of result are valid
__device__ __forceinline__ unsigned f2bf_cvt(float f){
  unsigned r;
  asm("v_cvt_pk_bf16_f32 %0, %1, %1" : "=v"(r) : "v"(f));
  return r;
}

// ---------------- weight conversion: fp32 -> bf16 in ws ----------------
// wgt layout (u16 elems):
//   whhT_b [384*128]  @0        (PRESCALED: rows<256 *SGC, rows>=256 *THC)
//   W1b    [128*96]   @49152    (96 = 68 padded, zeros)
//   W2b    [128*128]  @61440
//   Wf1b   [256*1152] @77824
//   Wf2b   [128*256]  @372736
//   Wf3b   [64*128]   @405504
//   whhN_b [192*64]   @413696   (PRESCALED: rows<128 *SGC, rows>=128 *THC)
__global__ __launch_bounds__(256) void k_prep(
    const float* __restrict__ Whh_t, const float* __restrict__ W1,
    const float* __restrict__ W2,    const float* __restrict__ Wf1,
    const float* __restrict__ Wf2,   const float* __restrict__ Wf3,
    const float* __restrict__ Whh_n,
    unsigned short* __restrict__ wgt)
{
  int i = blockIdx.x * 256 + threadIdx.x;
  if (i < 49152){
    int g = i >> 7;
    float s = (g < 256) ? SGC : THC;
    wgt[i] = f2bf(Whh_t[i] * s); return;
  }
  i -= 49152;
  if (i < 12288){ int r = i / 96, c = i % 96;
    wgt[49152 + i] = (c < 68) ? f2bf(W1[r*68 + c]) : (unsigned short)0; return; }
  i -= 12288;
  if (i < 16384){ wgt[61440 + i] = f2bf(W2[i]); return; }
  i -= 16384;
  if (i < 294912){ wgt[77824 + i] = f2bf(Wf1[i]); return; }
  i -= 294912;
  if (i < 32768){ wgt[372736 + i] = f2bf(Wf2[i]); return; }
  i -= 32768;
  if (i < 8192){ wgt[405504 + i] = f2bf(Wf3[i]); return; }
  i -= 8192;
  if (i < 12288){
    int g = i >> 6;
    float s = (g < 128) ? SGC : THC;
    wgt[413696 + i] = f2bf(Whh_n[i] * s); return;
  }
}

// ---------------- neighbor GRU + sector pooling ----------------
// 1024 blocks x 512 threads; block handles 2 batches (bi = tid>>8).
// LDS: whh [192][72] shared (27648) + per-batch 13312:
//   hall 4x[16][72] (9216) | xst [16][64] f32 transposed (4096).
// Pooling scratch ALIASES xst rows 0..9 (dead after the GRU loop).
// Total 54272 B -> 3 blocks/CU (24 waves/CU).
// NOTE: launch_bounds second arg MUST stay 4 — (512,6) clamped the
// allocator to 40 VGPR and spilled 160 MB/launch to scratch (round 6).
__global__ __launch_bounds__(512, 4) void k_gru_n(
    const float* __restrict__ ttraj, const float* __restrict__ ntraj,
    const float* __restrict__ rang,  const float* __restrict__ nmask,
    const float* __restrict__ Wih_n,
    const float* __restrict__ bih_n, const float* __restrict__ bhh_n,
    const unsigned short* __restrict__ wgt,
    unsigned short* __restrict__ sf)             // [16384][96] bf16
{
  __shared__ char smem[54272];
  const int tid = threadIdx.x;
  const int bi = tid >> 8, lt = tid & 255;
  const int w = lt >> 6, u = (lt >> 4) & 3, c = lt & 15;
  const int b = blockIdx.x * 2 + bi;
  const unsigned short* whhN_b = wgt + 413696;   // [192][64] prescaled

  unsigned short* whh  = (unsigned short*)smem;                 // [192][72]
  char* pb = smem + 27648 + bi * 13312;
  unsigned short* hall = (unsigned short*)pb;                   // 4 x [16][72]
  unsigned short* hb   = hall + w * 1152;
  float* xst  = (float*)(pb + 9216);                            // [16][64] transposed

  for (int i = tid; i < 1536; i += 512){
    int r = i >> 3, cg = (i & 7) * 8;
    *(short8*)&whh[r*72 + cg] = *(const short8*)&whhN_b[r*64 + cg];
  }
  {
    float4 v = ((const float4*)(ntraj + (size_t)b * 1024))[lt];
    int row = lt >> 2, p4 = (lt & 3) * 4;
    xst[(p4+0)*64 + row] = v.x;
    xst[(p4+1)*64 + row] = v.y;
    xst[(p4+2)*64 + row] = v.z;
    xst[(p4+3)*64 + row] = v.w;
  }
  __syncthreads();

  // per-lane gate constants, prescaled (gate col g = gt*16 + c)
  float wr0[4],wr1[4],br_[4],wz0[4],wz1[4],bz_[4],wn0[4],wn1[4],bi_[4],bh_[4];
#pragma unroll
  for (int gt = 0; gt < 4; ++gt){
    int g = gt*16 + c;
    wr0[gt]=Wih_n[g*2]*SGC;  wr1[gt]=Wih_n[g*2+1]*SGC;  br_[gt]=(bih_n[g]+bhh_n[g])*SGC;
    int gz = 64+g;  wz0[gt]=Wih_n[gz*2]*SGC; wz1[gt]=Wih_n[gz*2+1]*SGC; bz_[gt]=(bih_n[gz]+bhh_n[gz])*SGC;
    int gn = 128+g; wn0[gt]=Wih_n[gn*2]*THC; wn1[gt]=Wih_n[gn*2+1]*THC; bi_[gt]=bih_n[gn]*THC; bh_[gt]=bhh_n[gn]*THC;
  }
  float hcur[4][4];
#pragma unroll
  for (int gt=0; gt<4; ++gt)
#pragma unroll
    for (int q=0; q<4; ++q) hcur[gt][q] = 0.0f;

  float xq0[4], xq1[4];
  auto gates = [&](int gt, const f32x4& aR, const f32x4& aZ, const f32x4& aN){
#pragma unroll
    for (int q = 0; q < 4; ++q){
      float x0 = xq0[q], x1 = xq1[q];
      float rp = __builtin_fmaf(wr0[gt], x0, __builtin_fmaf(wr1[gt], x1, aR[q] + br_[gt]));
      float zp = __builtin_fmaf(wz0[gt], x0, __builtin_fmaf(wz1[gt], x1, aZ[q] + bz_[gt]));
      float r = __builtin_amdgcn_rcpf(1.0f + __builtin_amdgcn_exp2f(rp));
      float z = __builtin_amdgcn_rcpf(1.0f + __builtin_amdgcn_exp2f(zp));
      float hnv = aN[q] + bh_[gt];
      float pn = __builtin_fmaf(wn0[gt], x0, __builtin_fmaf(wn1[gt], x1, __builtin_fmaf(r, hnv, bi_[gt])));
      float E = __builtin_amdgcn_exp2f(pn);
      float n = __builtin_fmaf(-2.0f, __builtin_amdgcn_rcpf(E + 1.0f), 1.0f);
      float hnew = __builtin_fmaf(z, hcur[gt][q] - n, n);
      hcur[gt][q] = hnew;
      hb[(u*4+q)*72 + gt*16 + c] = (unsigned short)f2bf_cvt(hnew);
    }
  };

  for (int st = 0; st < 8; ++st){
#pragma unroll
    for (int q=0; q<4; ++q){
      int sq = w*16 + u*4 + q;
      xq0[q] = xst[st*128 + sq];
      xq1[q] = xst[st*128 + 64 + sq];
    }
    if (st > 0){
      short8 a0 = *(short8*)&hb[c*72 + u*8];
      short8 a1 = *(short8*)&hb[c*72 + 32 + u*8];
      f32x4 zz = {0.f,0.f,0.f,0.f};
#pragma unroll
      for (int gt = 0; gt < 4; ++gt){
        const unsigned short* pr = &whh[(gt*16+c)*72 + u*8];
        const unsigned short* pz = &whh[((4+gt)*16+c)*72 + u*8];
        const unsigned short* pq = &whh[((8+gt)*16+c)*72 + u*8];
        f32x4 aR = __builtin_amdgcn_mfma_f32_16x16x32_bf16(a0, *(const short8*)pr, zz, 0,0,0);
        aR = __builtin_amdgcn_mfma_f32_16x16x32_bf16(a1, *(const short8*)(pr+32), aR, 0,0,0);
        f32x4 aZ = __builtin_amdgcn_mfma_f32_16x16x32_bf16(a0, *(const short8*)pz, zz, 0,0,0);
        aZ = __builtin_amdgcn_mfma_f32_16x16x32_bf16(a1, *(const short8*)(pz+32), aZ, 0,0,0);
        f32x4 aN = __builtin_amdgcn_mfma_f32_16x16x32_bf16(a0, *(const short8*)pq, zz, 0,0,0);
        aN = __builtin_amdgcn_mfma_f32_16x16x32_bf16(a1, *(const short8*)(pq+32), aN, 0,0,0);
        gates(gt, aR, aZ, aN);
      }
    } else {
      f32x4 zz = {0.f,0.f,0.f,0.f};
#pragma unroll
      for (int gt = 0; gt < 4; ++gt) gates(gt, zz, zz, zz);
    }
  }
  __syncthreads();

  // ---- sector pooling (scratch aliased into xst rows 0..9) ----
  if (lt < 64){
    int n = lt;
    float m   = nmask[(size_t)b*64 + n];
    float ang = rang[(size_t)b*64 + n];
    float tx = ttraj[(size_t)b*16 + 14], ty = ttraj[(size_t)b*16 + 15];
    float px = xst[14*64+n], py = xst[15*64+n];
    float vx = px - xst[12*64+n], vy = py - xst[13*64+n];
    float dx = px - tx, dy = py - ty;
    float dist = __builtin_amdgcn_sqrtf(dx*dx + dy*dy);
    int sid = (int)(ang / 0.78539816339744830962f);
    sid = sid < 0 ? 0 : (sid > 7 ? 7 : sid);
    bool valid = m > 0.0f;
    float wv = valid ? __builtin_amdgcn_exp2f(dist * -0.14426950408889634f) : 0.0f;
    xst[0*64+n] = valid ? dist : 0.0f;
    xst[1*64+n] = valid ? vx   : 0.0f;
    xst[2*64+n] = valid ? vy   : 0.0f;
    xst[3*64+n] = wv;
    xst[4*64+n] = valid ? (float)sid : -1.0f;
  }
  __syncthreads();
  if (lt < 8){
    int s = lt;
    float cnt=0.f, sd=0.f, sx=0.f, sy=0.f, sw=0.f;
    for (int n=0; n<64; ++n){
      if (xst[4*64+n] == (float)s){
        cnt += 1.f; sd += xst[n]; sx += xst[64+n]; sy += xst[128+n]; sw += xst[192+n];
      }
    }
    float inv = (cnt > 0.f) ? __builtin_amdgcn_rcpf(cnt) : 0.f;
    xst[5*64+s] = cnt;
    xst[6*64+s] = sd * inv;
    xst[7*64+s] = sx * inv;
    xst[8*64+s] = sy * inv;
    xst[9*64+s] = __builtin_amdgcn_rcpf(sw + 1e-8f);
  }
  __syncthreads();
#pragma unroll
  for (int rep = 0; rep < 2; ++rep){
    int p = lt + rep*256;
    int s = p >> 6, h = p & 63;
    float fs = (float)s;
    float a = 0.f;
    for (int n = 0; n < 64; ++n){
      float wmv = (xst[4*64+n] == fs) ? xst[3*64+n] : 0.f;
      float nf  = bf2f(hall[(n>>4)*1152 + (n&15)*72 + h]);
      a += wmv * nf;
    }
    sf[((size_t)b*8 + s)*96 + 4 + h] = (unsigned short)f2bf_cvt(a * xst[9*64+s]);
  }
  if (lt < 32){
    int s = lt >> 2, cc = lt & 3;
    sf[((size_t)b*8 + s)*96 + cc] = (unsigned short)f2bf_cvt(xst[(5+cc)*64 + s]);
  }
  if (lt < 224){
    int s = lt / 28, cc = 68 + lt % 28;
    sf[((size_t)b*8 + s)*96 + cc] = 0;
  }
}

// ---------------- target GRU: 128 blocks x 256 thr (4 waves) ----------------
// Wave w owns hidden slice [w*32, w*32+32); B-frags register-resident.
// whhT_b is PRESCALED (r,z rows *SGC; n rows *THC).
__global__ __launch_bounds__(256) void k_gru_t(
    const float* __restrict__ ttraj,
    const float* __restrict__ Wih_t, const float* __restrict__ bih_t, const float* __restrict__ bhh_t,
    const unsigned short* __restrict__ wgt,      // whhT_b [384][128] @0
    unsigned short* __restrict__ combined)       // [2048][1152] bf16
{
  __shared__ char smem[9728];
  const int tid = threadIdx.x, w = tid >> 6, u = (tid >> 4) & 3, c = tid & 15;
  unsigned short* hb0 = (unsigned short*)smem;             // [16][136]
  unsigned short* hb1 = (unsigned short*)(smem + 4352);    // [16][136]
  float* xs = (float*)(smem + 8704);                       // [16][16]

  xs[tid] = ttraj[(size_t)blockIdx.x*256 + tid];

  int ntg[6];
  ntg[0] = 2*w; ntg[1] = 2*w+1;
  ntg[2] = 8+2*w; ntg[3] = 9+2*w;
  ntg[4] = 16+2*w; ntg[5] = 17+2*w;

  short8 Bf[6][4];
#pragma unroll
  for (int lt2 = 0; lt2 < 6; ++lt2){
    const unsigned short* wp = wgt + (ntg[lt2]*16 + c)*128 + u*8;
#pragma unroll
    for (int kk = 0; kk < 4; ++kk)
      Bf[lt2][kk] = *(const short8*)(wp + kk*32);
  }

  float Wr0[2],Wr1[2],BR[2],Wz0[2],Wz1[2],BZ[2],Wn0[2],Wn1[2],BI[2],BH[2];
#pragma unroll
  for (int gt = 0; gt < 2; ++gt){
    int g = w*32 + gt*16 + c;
    Wr0[gt]=Wih_t[g*2]*SGC;        Wr1[gt]=Wih_t[g*2+1]*SGC;        BR[gt]=(bih_t[g]+bhh_t[g])*SGC;
    Wz0[gt]=Wih_t[(128+g)*2]*SGC;  Wz1[gt]=Wih_t[(128+g)*2+1]*SGC;  BZ[gt]=(bih_t[128+g]+bhh_t[128+g])*SGC;
    Wn0[gt]=Wih_t[(256+g)*2]*THC;  Wn1[gt]=Wih_t[(256+g)*2+1]*THC;  BI[gt]=bih_t[256+g]*THC; BH[gt]=bhh_t[256+g]*THC;
  }
  float hcur[2][4];
#pragma unroll
  for (int gt=0; gt<2; ++gt)
#pragma unroll
    for (int q=0; q<4; ++q) hcur[gt][q] = 0.0f;
  __syncthreads();

  for (int st = 0; st < 8; ++st){
    unsigned short* rbuf = (st & 1) ? hb0 : hb1;
    unsigned short* wbuf = (st & 1) ? hb1 : hb0;
    f32x4 acc[6];
    if (st > 0){
      short8 a0 = *(short8*)&rbuf[c*136 + u*8];
      short8 a1 = *(short8*)&rbuf[c*136 + 32 + u*8];
      short8 a2 = *(short8*)&rbuf[c*136 + 64 + u*8];
      short8 a3 = *(short8*)&rbuf[c*136 + 96 + u*8];
#pragma unroll
      for (int lt2 = 0; lt2 < 6; ++lt2){
        f32x4 t = {0.f,0.f,0.f,0.f};
        t = __builtin_amdgcn_mfma_f32_16x16x32_bf16(a0, Bf[lt2][0], t, 0,0,0);
        t = __builtin_amdgcn_mfma_f32_16x16x32_bf16(a1, Bf[lt2][1], t, 0,0,0);
        t = __builtin_amdgcn_mfma_f32_16x16x32_bf16(a2, Bf[lt2][2], t, 0,0,0);
        acc[lt2] = __builtin_amdgcn_mfma_f32_16x16x32_bf16(a3, Bf[lt2][3], t, 0,0,0);
      }
    } else {
#pragma unroll
      for (int lt2 = 0; lt2 < 6; ++lt2) acc[lt2] = (f32x4){0.f,0.f,0.f,0.f};
    }
#pragma unroll
    for (int gt = 0; gt < 2; ++gt){
#pragma unroll
      for (int q = 0; q < 4; ++q){
        int sq = u*4 + q;
        float x0 = xs[sq*16 + st*2], x1 = xs[sq*16 + st*2 + 1];
        float rp = __builtin_fmaf(Wr0[gt], x0, __builtin_fmaf(Wr1[gt], x1, acc[gt][q] + BR[gt]));
        float zp = __builtin_fmaf(Wz0[gt], x0, __builtin_fmaf(Wz1[gt], x1, acc[2+gt][q] + BZ[gt]));
        float r = __builtin_amdgcn_rcpf(1.0f + __builtin_amdgcn_exp2f(rp));
        float z = __builtin_amdgcn_rcpf(1.0f + __builtin_amdgcn_exp2f(zp));
        float hnv = acc[4+gt][q] + BH[gt];
        float pn = __builtin_fmaf(Wn0[gt], x0, __builtin_fmaf(Wn1[gt], x1, __builtin_fmaf(r, hnv, BI[gt])));
        float E = __builtin_amdgcn_exp2f(pn);
        float n = __builtin_fmaf(-2.0f, __builtin_amdgcn_rcpf(E + 1.0f), 1.0f);
        float hnew = __builtin_fmaf(z, hcur[gt][q] - n, n);
        hcur[gt][q] = hnew;
        if (st < 7){
          wbuf[sq*136 + w*32 + gt*16 + c] = (unsigned short)f2bf_cvt(hnew);
        } else {
          int row = blockIdx.x*16 + sq;
          combined[(size_t)row*1152 + w*32 + gt*16 + c] = (unsigned short)f2bf_cvt(hnew);
        }
      }
    }
    if (st < 7) __syncthreads();
  }
}

// ---------------- MLP1/MLP2 over (b,s) rows: sf -> enc part of combined ----------------
__global__ __launch_bounds__(256) void k_mlp12(
    const unsigned short* __restrict__ sf,    // [16384][96]
    const unsigned short* __restrict__ wgt,
    const float* __restrict__ b1, const float* __restrict__ b2,
    unsigned short* __restrict__ combined)
{
  __shared__ char smem[18432];
  unsigned short* hb = (unsigned short*)smem + (threadIdx.x >> 6) * 2176;  // [16][136]/wave
  float* b1s = (float*)(smem + 17408);
  float* b2s = b1s + 128;
  const unsigned short* w1b = wgt + 49152;
  const unsigned short* w2b = wgt + 61440;
  const int tid = threadIdx.x, w = tid >> 6, u = (tid >> 4) & 3, c = tid & 15;
  if (tid < 128){ b1s[tid] = b1[tid]; b2s[tid] = b2[tid]; }
  __syncthreads();
  const int rowb = blockIdx.x * 64 + w * 16;

  f32x4 acc[8];
#pragma unroll
  for (int nt=0; nt<8; ++nt) acc[nt] = (f32x4){0.f,0.f,0.f,0.f};
#pragma unroll
  for (int kc=0; kc<3; ++kc){
    short8 a = *(const short8*)&sf[(size_t)(rowb + c)*96 + kc*32 + u*8];
#pragma unroll
    for (int nt=0; nt<8; ++nt){
      short8 bb = *(const short8*)&w1b[(nt*16+c)*96 + kc*32 + u*8];
      acc[nt] = __builtin_amdgcn_mfma_f32_16x16x32_bf16(a, bb, acc[nt], 0,0,0);
    }
  }
#pragma unroll
  for (int nt=0; nt<8; ++nt){
    float bias = b1s[nt*16+c];
#pragma unroll
    for (int q=0; q<4; ++q){
      float v = acc[nt][q] + bias; v = v > 0.f ? v : 0.f;
      hb[(u*4+q)*136 + nt*16 + c] = (unsigned short)f2bf_cvt(v);
    }
  }
  f32x4 acc2[8];
#pragma unroll
  for (int nt=0; nt<8; ++nt) acc2[nt] = (f32x4){0.f,0.f,0.f,0.f};
#pragma unroll
  for (int kc=0; kc<4; ++kc){
    short8 a = *(short8*)&hb[c*136 + kc*32 + u*8];
#pragma unroll
    for (int nt=0; nt<8; ++nt){
      short8 bb = *(const short8*)&w2b[(nt*16+c)*128 + kc*32 + u*8];
      acc2[nt] = __builtin_amdgcn_mfma_f32_16x16x32_bf16(a, bb, acc2[nt], 0,0,0);
    }
  }
#pragma unroll
  for (int nt=0; nt<8; ++nt){
    float bias = b2s[nt*16+c];
#pragma unroll
    for (int q=0; q<4; ++q){
      float v = acc2[nt][q] + bias; v = v > 0.f ? v : 0.f;
      int r = rowb + u*4 + q;
      combined[(size_t)(r >> 3)*1152 + 128 + (r & 7)*128 + nt*16 + c] = (unsigned short)f2bf_cvt(v);
    }
  }
}

// ---------------- head v2: 128 blocks x 256 thr (4 waves) ----------------
__global__ __launch_bounds__(256) void k_head(
    const unsigned short* __restrict__ combined,
    const unsigned short* __restrict__ wgt,
    const float* __restrict__ bf1, const float* __restrict__ bf2, const float* __restrict__ bf3,
    const float* __restrict__ lng, const float* __restrict__ lnb,
    float* __restrict__ out)
{
  __shared__ char smem[15104];
  const int tid = threadIdx.x, w = tid >> 6, u = (tid >> 4) & 3, c = tid & 15;
  unsigned short* f1b = (unsigned short*)smem;                 // [16][264]
  unsigned short* f2b = (unsigned short*)(smem + 8448);        // [16][136]
  float* bf1s = (float*)(smem + 12800); float* bf2s = (float*)(smem + 13824);
  float* bf3s = (float*)(smem + 14336);
  float* lngs = (float*)(smem + 14592); float* lnbs = (float*)(smem + 14848);
  const unsigned short* wf1b = wgt + 77824;
  const unsigned short* wf2b = wgt + 372736;
  const unsigned short* wf3b = wgt + 405504;
  bf1s[tid] = bf1[tid];
  if (tid < 128) bf2s[tid] = bf2[tid];
  if (tid < 64){ bf3s[tid] = bf3[tid]; lngs[tid] = lng[tid]; lnbs[tid] = lnb[tid]; }
  __syncthreads();
  const int rowb = blockIdx.x * 16;

  f32x4 acc[4];
#pragma unroll
  for (int i=0; i<4; ++i) acc[i] = (f32x4){0.f,0.f,0.f,0.f};
#pragma unroll 4
  for (int kc=0; kc<36; ++kc){
    short8 a = *(const short8*)&combined[(size_t)(rowb + c)*1152 + kc*32 + u*8];
#pragma unroll
    for (int i=0; i<4; ++i){
      int nt = w*4 + i;
      short8 bb = *(const short8*)&wf1b[(size_t)(nt*16+c)*1152 + kc*32 + u*8];
      acc[i] = __builtin_amdgcn_mfma_f32_16x16x32_bf16(a, bb, acc[i], 0,0,0);
    }
  }
#pragma unroll
  for (int i=0; i<4; ++i){
    int nt = w*4 + i;
    float bias = bf1s[nt*16+c];
#pragma unroll
    for (int q=0; q<4; ++q){
      float v = acc[i][q] + bias; v = v > 0.f ? v : 0.f;
      f1b[(u*4+q)*264 + nt*16 + c] = (unsigned short)f2bf_cvt(v);
    }
  }
  __syncthreads();

  f32x4 acc2[2];
#pragma unroll
  for (int i=0; i<2; ++i) acc2[i] = (f32x4){0.f,0.f,0.f,0.f};
#pragma unroll
  for (int kc=0; kc<8; ++kc){
    short8 a = *(short8*)&f1b[c*264 + kc*32 + u*8];
#pragma unroll
    for (int i=0; i<2; ++i){
      int nt = w*2 + i;
      short8 bb = *(const short8*)&wf2b[(nt*16+c)*256 + kc*32 + u*8];
      acc2[i] = __builtin_amdgcn_mfma_f32_16x16x32_bf16(a, bb, acc2[i], 0,0,0);
    }
  }
#pragma unroll
  for (int i=0; i<2; ++i){
    int nt = w*2 + i;
    float bias = bf2s[nt*16+c];
#pragma unroll
    for (int q=0; q<4; ++q){
      float v = acc2[i][q] + bias; v = v > 0.f ? v : 0.f;
      f2b[(u*4+q)*136 + nt*16 + c] = (unsigned short)f2bf_cvt(v);
    }
  }
  __syncthreads();

  f32x4 acc3[4];
#pragma unroll
  for (int nt=0; nt<4; ++nt) acc3[nt] = (f32x4){0.f,0.f,0.f,0.f};
#pragma unroll
  for (int kc=0; kc<4; ++kc){
    short8 a = *(short8*)&f2b[c*136 + kc*32 + u*8];
#pragma unroll
    for (int nt=0; nt<4; ++nt){
      short8 bb = *(const short8*)&wf3b[(nt*16+c)*128 + kc*32 + u*8];
      acc3[nt] = __builtin_amdgcn_mfma_f32_16x16x32_bf16(a, bb, acc3[nt], 0,0,0);
    }
  }
  if (w == 0){
    float v[4][4];
#pragma unroll
    for (int nt=0; nt<4; ++nt){
      float bias = bf3s[nt*16+c];
#pragma unroll
      for (int q=0; q<4; ++q){
        float t = acc3[nt][q] + bias; v[nt][q] = t > 0.f ? t : 0.f;
      }
    }
#pragma unroll
    for (int q=0; q<4; ++q){
      float p = v[0][q] + v[1][q] + v[2][q] + v[3][q];
      p += __shfl_xor(p, 1); p += __shfl_xor(p, 2); p += __shfl_xor(p, 4); p += __shfl_xor(p, 8);
      float mu = p * 0.015625f;
      float d0 = v[0][q]-mu, d1 = v[1][q]-mu, d2 = v[2][q]-mu, d3 = v[3][q]-mu;
      float p2 = d0*d0 + d1*d1 + d2*d2 + d3*d3;
      p2 += __shfl_xor(p2, 1); p2 += __shfl_xor(p2, 2); p2 += __shfl_xor(p2, 4); p2 += __shfl_xor(p2, 8);
      float rstd = __builtin_amdgcn_rsqf(p2 * 0.015625f + 1e-5f);
      int row = rowb + u*4 + q;
#pragma unroll
      for (int nt=0; nt<4; ++nt){
        int col = nt*16 + c;
        out[(size_t)row*64 + col] = (v[nt][q] - mu) * rstd * lngs[col] + lnbs[col];
      }
    }
  }
}

extern "C" void kernel_launch(void* const* d_in, const int* in_sizes, int n_in,
                              void* d_out, int out_size, void* d_ws, size_t ws_size,
                              hipStream_t stream)
{
  const float* ttraj = (const float*)d_in[0];
  const float* ntraj = (const float*)d_in[1];
  const float* rang  = (const float*)d_in[2];
  const float* nmask = (const float*)d_in[3];
  const float* Wih_t = (const float*)d_in[4];
  const float* Whh_t = (const float*)d_in[5];
  const float* bih_t = (const float*)d_in[6];
  const float* bhh_t = (const float*)d_in[7];
  const float* Wih_n = (const float*)d_in[8];
  const float* Whh_n = (const float*)d_in[9];
  const float* bih_n = (const float*)d_in[10];
  const float* bhh_n = (const float*)d_in[11];
  const float* W1  = (const float*)d_in[12];
  const float* b1  = (const float*)d_in[13];
  const float* W2  = (const float*)d_in[14];
  const float* b2  = (const float*)d_in[15];
  const float* Wf1 = (const float*)d_in[16];
  const float* bf1 = (const float*)d_in[17];
  const float* Wf2 = (const float*)d_in[18];
  const float* bf2 = (const float*)d_in[19];
  const float* Wf3 = (const float*)d_in[20];
  const float* bf3 = (const float*)d_in[21];
  const float* lng = (const float*)d_in[22];
  const float* lnb = (const float*)d_in[23];

  char* ws = (char*)d_ws;
  unsigned short* combined = (unsigned short*)ws;                  // [2048][1152] bf16
  unsigned short* sf       = (unsigned short*)(ws + 5242880);      // [16384][96] bf16
  unsigned short* wgt      = (unsigned short*)(ws + 8388608);      // bf16 weights

  hipLaunchKernelGGL(k_prep, dim3(1664), dim3(256), 0, stream,
                     Whh_t, W1, W2, Wf1, Wf2, Wf3, Whh_n, wgt);
  hipLaunchKernelGGL(k_gru_n, dim3(1024), dim3(512), 0, stream,
                     ttraj, ntraj, rang, nmask, Wih_n, bih_n, bhh_n, wgt, sf);
  hipLaunchKernelGGL(k_gru_t, dim3(128), dim3(256), 0, stream,
                     ttraj, Wih_t, bih_t, bhh_t, wgt, combined);
  hipLaunchKernelGGL(k_mlp12, dim3(256), dim3(256), 0, stream, sf, wgt, b1, b2, combined);
  hipLaunchKernelGGL(k_head, dim3(128), dim3(256), 0, stream,
                     combined, wgt, bf1, bf2, bf3, lng, lnb, (float*)d_out);
}

// Round 8
// 135.168 us; speedup vs baseline: 1.2932x; 1.0573x over previous
//
#include <hip/hip_runtime.h>

typedef __attribute__((ext_vector_type(8))) short short8;
typedef __attribute__((ext_vector_type(4))) float f32x4;

#define SGC (-1.44269504088896341f)   /* -log2(e): sigmoid prescale */
#define THC ( 2.88539008177792681f)   /* 2*log2(e): tanh prescale   */

__device__ __forceinline__ unsigned short f2bf(float f){
  unsigned u = __float_as_uint(f);
  return (unsigned short)((u + 0x7fffu + ((u >> 16) & 1u)) >> 16);
}
__device__ __forceinline__ float bf2f(unsigned short b){
  return __uint_as_float(((unsigned)b) << 16);
}
// single f32 -> bf16 (RNE) in one VALU op; low 16 bits of result are valid
__device__ __forceinline__ unsigned f2bf_cvt(float f){
  unsigned r;
  asm("v_cvt_pk_bf16_f32 %0, %1, %1" : "=v"(r) : "v"(f));
  return r;
}
__device__ __forceinline__ unsigned f2bf_pk(float lo, float hi){
  unsigned r;
  asm("v_cvt_pk_bf16_f32 %0, %1, %2" : "=v"(r) : "v"(lo), "v"(hi));
  return r;
}

// ---------------- weight conversion: fp32 -> bf16 in ws ----------------
// wgt layout (u16 elems):
//   whhT_b [384*128]  @0        (PRESCALED: rows<256 *SGC, rows>=256 *THC)
//   W1b    [128*96]   @49152    (96 = 68 padded, zeros)
//   W2b    [128*128]  @61440
//   Wf1b   [256*1152] @77824
//   Wf2b   [128*256]  @372736
//   Wf3b   [64*128]   @405504
//   whhN_b [192*64]   @413696   (PRESCALED: rows<128 *SGC, rows>=128 *THC)
__global__ __launch_bounds__(256) void k_prep(
    const float* __restrict__ Whh_t, const float* __restrict__ W1,
    const float* __restrict__ W2,    const float* __restrict__ Wf1,
    const float* __restrict__ Wf2,   const float* __restrict__ Wf3,
    const float* __restrict__ Whh_n,
    unsigned short* __restrict__ wgt)
{
  int i = blockIdx.x * 256 + threadIdx.x;
  if (i < 49152){
    int g = i >> 7;
    float s = (g < 256) ? SGC : THC;
    wgt[i] = f2bf(Whh_t[i] * s); return;
  }
  i -= 49152;
  if (i < 12288){ int r = i / 96, c = i % 96;
    wgt[49152 + i] = (c < 68) ? f2bf(W1[r*68 + c]) : (unsigned short)0; return; }
  i -= 12288;
  if (i < 16384){ wgt[61440 + i] = f2bf(W2[i]); return; }
  i -= 16384;
  if (i < 294912){ wgt[77824 + i] = f2bf(Wf1[i]); return; }
  i -= 294912;
  if (i < 32768){ wgt[372736 + i] = f2bf(Wf2[i]); return; }
  i -= 32768;
  if (i < 8192){ wgt[405504 + i] = f2bf(Wf3[i]); return; }
  i -= 8192;
  if (i < 12288){
    int g = i >> 6;
    float s = (g < 128) ? SGC : THC;
    wgt[413696 + i] = f2bf(Whh_n[i] * s); return;
  }
}

// ---------------- neighbor GRU + sector pooling ----------------
// 1024 blocks x 512 threads; block handles 2 batches (bi = tid>>8).
// x-projection + biases FOLDED INTO MFMA (K=96 augmentation):
//   A row = [h(64), x0, x1, 1.0, 0...]; 12 hh tiles lane-linear +
//   12 tiny x-tiles (256 B each: rows 64=W0*s,65=W1*s,66=bias*s).
// LDS: whh2 [12][2][64][8] (24576) | wx [12][16][8] (3072) |
//      per-batch: hall 4x[16][72] (9216) + xst [8][64][2] f32 (4096).
// Total 54272 B. Pooling scratch aliases xst steps 0..2.
// NOTE: launch_bounds 2nd arg stays 4 — (512,6) caused 40-VGPR spill (r6).
__global__ __launch_bounds__(512, 4) void k_gru_n(
    const float* __restrict__ ttraj, const float* __restrict__ ntraj,
    const float* __restrict__ rang,  const float* __restrict__ nmask,
    const float* __restrict__ Wih_n,
    const float* __restrict__ bih_n, const float* __restrict__ bhh_n,
    const unsigned short* __restrict__ wgt,
    unsigned short* __restrict__ sf)             // [16384][96] bf16
{
  __shared__ char smem[54272];
  const int tid = threadIdx.x;
  const int bi = tid >> 8, lt = tid & 255;
  const int w = lt >> 6, u = (lt >> 4) & 3, c = lt & 15;
  const int b = blockIdx.x * 2 + bi;
  const unsigned short* whhN_b = wgt + 413696;   // [192][64] prescaled

  unsigned short* whh2 = (unsigned short*)smem;                 // [12][2][64][8]
  unsigned short* wx   = whh2 + 12288;                          // [12][16][8]
  char* pb = smem + 27648 + bi * 13312;
  unsigned short* hall = (unsigned short*)pb;                   // 4 x [16][72]
  unsigned short* hb   = hall + w * 1152;
  float* xst  = (float*)(pb + 9216);                            // [8][64][2]

  // stage hh weights lane-linear: whh2[nt][half][u*16+c][8]
  for (int i = tid; i < 1536; i += 512){
    int nt = i >> 7, rem = i & 127;
    int hf = rem >> 6, uu = (rem >> 4) & 3, cc = rem & 15;
    *(short8*)&whh2[nt*1024 + hf*512 + (uu*16+cc)*8] =
        *(const short8*)&whhN_b[(nt*16+cc)*64 + hf*32 + uu*8];
  }
  // stage x-tiles: rows 64,65,66 = W0*s, W1*s, bias*s (rest 0)
  if (tid < 192){
    int t = tid >> 4, cc = tid & 15;
    float s = (t < 8) ? SGC : THC;
    int g = (t < 4) ? (t*16 + cc) : (t < 8) ? (64 + (t-4)*16 + cc) : (128 + (t-8)*16 + cc);
    float bsum = (t < 8) ? (bih_n[g] + bhh_n[g]) : bih_n[g];
    unsigned short* p = &wx[t*128 + cc*8];
    *(short8*)p = (short8){0,0,0,0,0,0,0,0};
    p[0] = f2bf(Wih_n[g*2]   * s);
    p[1] = f2bf(Wih_n[g*2+1] * s);
    p[2] = f2bf(bsum * s);
  }
  // stage trajectories: xst[step][seq][2]
  {
    float4 v = ((const float4*)(ntraj + (size_t)b * 1024))[lt];
    int seq = lt >> 2, s0 = (lt & 3) * 2;
    xst[s0*128 + seq*2]       = v.x;
    xst[s0*128 + seq*2 + 1]   = v.y;
    xst[(s0+1)*128 + seq*2]   = v.z;
    xst[(s0+1)*128 + seq*2+1] = v.w;
  }
  __syncthreads();

  float bh_[4];
#pragma unroll
  for (int gt = 0; gt < 4; ++gt) bh_[gt] = bhh_n[128 + gt*16 + c] * THC;

  float hcur[4][4];
#pragma unroll
  for (int gt=0; gt<4; ++gt)
#pragma unroll
    for (int q=0; q<4; ++q) hcur[gt][q] = 0.0f;

  auto gates = [&](int gt, const f32x4& aR, const f32x4& aZ, const f32x4& aN, const f32x4& aX){
#pragma unroll
    for (int q = 0; q < 4; ++q){
      float r = __builtin_amdgcn_rcpf(1.0f + __builtin_amdgcn_exp2f(aR[q]));
      float z = __builtin_amdgcn_rcpf(1.0f + __builtin_amdgcn_exp2f(aZ[q]));
      float hn = aN[q] + bh_[gt];
      float pn = __builtin_fmaf(r, hn, aX[q]);
      float E = __builtin_amdgcn_exp2f(pn);
      float n = __builtin_fmaf(-2.0f, __builtin_amdgcn_rcpf(E + 1.0f), 1.0f);
      float hnew = __builtin_fmaf(z, hcur[gt][q] - n, n);
      hcur[gt][q] = hnew;
      hb[(u*4+q)*72 + gt*16 + c] = (unsigned short)f2bf_cvt(hnew);
    }
  };

  const int lane8 = (u*16 + c) * 8;
  const f32x4 zz = {0.f,0.f,0.f,0.f};

  for (int st = 0; st < 8; ++st){
    // build augmented A chunk a2 = [x0, x1, 1.0, 0...] (u==0 lanes only)
    float2 xv = *(const float2*)&xst[st*128 + (w*16+c)*2];
    unsigned p01 = f2bf_pk(xv.x, xv.y);
    bool u0 = (u == 0);
    union { unsigned ui[4]; short8 s8; } a2u;
    a2u.ui[0] = u0 ? p01 : 0u;
    a2u.ui[1] = u0 ? 0x3F80u : 0u;   // bf16(1.0) in halfword 2
    a2u.ui[2] = 0u; a2u.ui[3] = 0u;
    short8 a2 = a2u.s8;

    if (st > 0){
      short8 a0 = *(short8*)&hb[c*72 + u*8];
      short8 a1 = *(short8*)&hb[c*72 + 32 + u*8];
#pragma unroll
      for (int gt = 0; gt < 4; ++gt){
        const unsigned short* pr = whh2 + gt*1024 + lane8;
        const unsigned short* pz = whh2 + (4+gt)*1024 + lane8;
        const unsigned short* pq = whh2 + (8+gt)*1024 + lane8;
        short8 bxr = *(const short8*)&wx[gt*128 + c*8];
        short8 bxz = *(const short8*)&wx[(4+gt)*128 + c*8];
        short8 bxn = *(const short8*)&wx[(8+gt)*128 + c*8];
        f32x4 aR = __builtin_amdgcn_mfma_f32_16x16x32_bf16(a0, *(const short8*)pr, zz, 0,0,0);
        aR = __builtin_amdgcn_mfma_f32_16x16x32_bf16(a1, *(const short8*)(pr+512), aR, 0,0,0);
        aR = __builtin_amdgcn_mfma_f32_16x16x32_bf16(a2, bxr, aR, 0,0,0);
        f32x4 aZ = __builtin_amdgcn_mfma_f32_16x16x32_bf16(a0, *(const short8*)pz, zz, 0,0,0);
        aZ = __builtin_amdgcn_mfma_f32_16x16x32_bf16(a1, *(const short8*)(pz+512), aZ, 0,0,0);
        aZ = __builtin_amdgcn_mfma_f32_16x16x32_bf16(a2, bxz, aZ, 0,0,0);
        f32x4 aN = __builtin_amdgcn_mfma_f32_16x16x32_bf16(a0, *(const short8*)pq, zz, 0,0,0);
        aN = __builtin_amdgcn_mfma_f32_16x16x32_bf16(a1, *(const short8*)(pq+512), aN, 0,0,0);
        f32x4 aX = __builtin_amdgcn_mfma_f32_16x16x32_bf16(a2, bxn, zz, 0,0,0);
        gates(gt, aR, aZ, aN, aX);
      }
    } else {
#pragma unroll
      for (int gt = 0; gt < 4; ++gt){
        short8 bxr = *(const short8*)&wx[gt*128 + c*8];
        short8 bxz = *(const short8*)&wx[(4+gt)*128 + c*8];
        short8 bxn = *(const short8*)&wx[(8+gt)*128 + c*8];
        f32x4 aR = __builtin_amdgcn_mfma_f32_16x16x32_bf16(a2, bxr, zz, 0,0,0);
        f32x4 aZ = __builtin_amdgcn_mfma_f32_16x16x32_bf16(a2, bxz, zz, 0,0,0);
        f32x4 aX = __builtin_amdgcn_mfma_f32_16x16x32_bf16(a2, bxn, zz, 0,0,0);
        gates(gt, aR, aZ, zz, aX);
      }
    }
  }
  __syncthreads();

  // ---- sector pooling (scratch aliased into xst steps 0..2) ----
  // dist@[0..63] vx@[64..127] vy@[128..191] wv@[192..255] sid@[256..319]
  // sect: cnt@[320+s] avgd@[328+s] avx@[336+s] avy@[344+s] winv@[352+s]
  if (lt < 64){
    int n = lt;
    float m   = nmask[(size_t)b*64 + n];
    float ang = rang[(size_t)b*64 + n];
    float tx = ttraj[(size_t)b*16 + 14], ty = ttraj[(size_t)b*16 + 15];
    float px = xst[7*128 + n*2], py = xst[7*128 + n*2 + 1];
    float vx = px - xst[6*128 + n*2], vy = py - xst[6*128 + n*2 + 1];
    float dx = px - tx, dy = py - ty;
    float dist = __builtin_amdgcn_sqrtf(dx*dx + dy*dy);
    int sid = (int)(ang / 0.78539816339744830962f);
    sid = sid < 0 ? 0 : (sid > 7 ? 7 : sid);
    bool valid = m > 0.0f;
    float wv = valid ? __builtin_amdgcn_exp2f(dist * -0.14426950408889634f) : 0.0f;
    xst[n]       = valid ? dist : 0.0f;
    xst[64 + n]  = valid ? vx   : 0.0f;
    xst[128 + n] = valid ? vy   : 0.0f;
    xst[192 + n] = wv;
    xst[256 + n] = valid ? (float)sid : -1.0f;
  }
  __syncthreads();
  if (lt < 8){
    int s = lt;
    float cnt=0.f, sd=0.f, sx=0.f, sy=0.f, sw=0.f;
    for (int n=0; n<64; ++n){
      if (xst[256+n] == (float)s){
        cnt += 1.f; sd += xst[n]; sx += xst[64+n]; sy += xst[128+n]; sw += xst[192+n];
      }
    }
    float inv = (cnt > 0.f) ? __builtin_amdgcn_rcpf(cnt) : 0.f;
    xst[320 + s] = cnt;
    xst[328 + s] = sd * inv;
    xst[336 + s] = sx * inv;
    xst[344 + s] = sy * inv;
    xst[352 + s] = __builtin_amdgcn_rcpf(sw + 1e-8f);
  }
  __syncthreads();
#pragma unroll
  for (int rep = 0; rep < 2; ++rep){
    int p = lt + rep*256;
    int s = p >> 6, h = p & 63;
    float fs = (float)s;
    float a = 0.f;
    for (int n = 0; n < 64; ++n){
      float wmv = (xst[256+n] == fs) ? xst[192+n] : 0.f;
      float nf  = bf2f(hall[(n>>4)*1152 + (n&15)*72 + h]);
      a += wmv * nf;
    }
    sf[((size_t)b*8 + s)*96 + 4 + h] = (unsigned short)f2bf_cvt(a * xst[352+s]);
  }
  if (lt < 32){
    int s = lt >> 2, cc = lt & 3;
    sf[((size_t)b*8 + s)*96 + cc] = (unsigned short)f2bf_cvt(xst[320 + cc*8 + s]);
  }
  if (lt < 224){
    int s = lt / 28, cc = 68 + lt % 28;
    sf[((size_t)b*8 + s)*96 + cc] = 0;
  }
}

// ---------------- target GRU: 128 blocks x 256 thr (4 waves) ----------------
// Wave w owns hidden slice [w*32, w*32+32); B-frags register-resident.
// whhT_b is PRESCALED (r,z rows *SGC; n rows *THC).
__global__ __launch_bounds__(256) void k_gru_t(
    const float* __restrict__ ttraj,
    const float* __restrict__ Wih_t, const float* __restrict__ bih_t, const float* __restrict__ bhh_t,
    const unsigned short* __restrict__ wgt,      // whhT_b [384][128] @0
    unsigned short* __restrict__ combined)       // [2048][1152] bf16
{
  __shared__ char smem[9728];
  const int tid = threadIdx.x, w = tid >> 6, u = (tid >> 4) & 3, c = tid & 15;
  unsigned short* hb0 = (unsigned short*)smem;             // [16][136]
  unsigned short* hb1 = (unsigned short*)(smem + 4352);    // [16][136]
  float* xs = (float*)(smem + 8704);                       // [16][16]

  xs[tid] = ttraj[(size_t)blockIdx.x*256 + tid];

  int ntg[6];
  ntg[0] = 2*w; ntg[1] = 2*w+1;
  ntg[2] = 8+2*w; ntg[3] = 9+2*w;
  ntg[4] = 16+2*w; ntg[5] = 17+2*w;

  short8 Bf[6][4];
#pragma unroll
  for (int lt2 = 0; lt2 < 6; ++lt2){
    const unsigned short* wp = wgt + (ntg[lt2]*16 + c)*128 + u*8;
#pragma unroll
    for (int kk = 0; kk < 4; ++kk)
      Bf[lt2][kk] = *(const short8*)(wp + kk*32);
  }

  float Wr0[2],Wr1[2],BR[2],Wz0[2],Wz1[2],BZ[2],Wn0[2],Wn1[2],BI[2],BH[2];
#pragma unroll
  for (int gt = 0; gt < 2; ++gt){
    int g = w*32 + gt*16 + c;
    Wr0[gt]=Wih_t[g*2]*SGC;        Wr1[gt]=Wih_t[g*2+1]*SGC;        BR[gt]=(bih_t[g]+bhh_t[g])*SGC;
    Wz0[gt]=Wih_t[(128+g)*2]*SGC;  Wz1[gt]=Wih_t[(128+g)*2+1]*SGC;  BZ[gt]=(bih_t[128+g]+bhh_t[128+g])*SGC;
    Wn0[gt]=Wih_t[(256+g)*2]*THC;  Wn1[gt]=Wih_t[(256+g)*2+1]*THC;  BI[gt]=bih_t[256+g]*THC; BH[gt]=bhh_t[256+g]*THC;
  }
  float hcur[2][4];
#pragma unroll
  for (int gt=0; gt<2; ++gt)
#pragma unroll
    for (int q=0; q<4; ++q) hcur[gt][q] = 0.0f;
  __syncthreads();

  for (int st = 0; st < 8; ++st){
    unsigned short* rbuf = (st & 1) ? hb0 : hb1;
    unsigned short* wbuf = (st & 1) ? hb1 : hb0;
    f32x4 acc[6];
    if (st > 0){
      short8 a0 = *(short8*)&rbuf[c*136 + u*8];
      short8 a1 = *(short8*)&rbuf[c*136 + 32 + u*8];
      short8 a2 = *(short8*)&rbuf[c*136 + 64 + u*8];
      short8 a3 = *(short8*)&rbuf[c*136 + 96 + u*8];
#pragma unroll
      for (int lt2 = 0; lt2 < 6; ++lt2){
        f32x4 t = {0.f,0.f,0.f,0.f};
        t = __builtin_amdgcn_mfma_f32_16x16x32_bf16(a0, Bf[lt2][0], t, 0,0,0);
        t = __builtin_amdgcn_mfma_f32_16x16x32_bf16(a1, Bf[lt2][1], t, 0,0,0);
        t = __builtin_amdgcn_mfma_f32_16x16x32_bf16(a2, Bf[lt2][2], t, 0,0,0);
        acc[lt2] = __builtin_amdgcn_mfma_f32_16x16x32_bf16(a3, Bf[lt2][3], t, 0,0,0);
      }
    } else {
#pragma unroll
      for (int lt2 = 0; lt2 < 6; ++lt2) acc[lt2] = (f32x4){0.f,0.f,0.f,0.f};
    }
#pragma unroll
    for (int gt = 0; gt < 2; ++gt){
#pragma unroll
      for (int q = 0; q < 4; ++q){
        int sq = u*4 + q;
        float x0 = xs[sq*16 + st*2], x1 = xs[sq*16 + st*2 + 1];
        float rp = __builtin_fmaf(Wr0[gt], x0, __builtin_fmaf(Wr1[gt], x1, acc[gt][q] + BR[gt]));
        float zp = __builtin_fmaf(Wz0[gt], x0, __builtin_fmaf(Wz1[gt], x1, acc[2+gt][q] + BZ[gt]));
        float r = __builtin_amdgcn_rcpf(1.0f + __builtin_amdgcn_exp2f(rp));
        float z = __builtin_amdgcn_rcpf(1.0f + __builtin_amdgcn_exp2f(zp));
        float hnv = acc[4+gt][q] + BH[gt];
        float pn = __builtin_fmaf(Wn0[gt], x0, __builtin_fmaf(Wn1[gt], x1, __builtin_fmaf(r, hnv, BI[gt])));
        float E = __builtin_amdgcn_exp2f(pn);
        float n = __builtin_fmaf(-2.0f, __builtin_amdgcn_rcpf(E + 1.0f), 1.0f);
        float hnew = __builtin_fmaf(z, hcur[gt][q] - n, n);
        hcur[gt][q] = hnew;
        if (st < 7){
          wbuf[sq*136 + w*32 + gt*16 + c] = (unsigned short)f2bf_cvt(hnew);
        } else {
          int row = blockIdx.x*16 + sq;
          combined[(size_t)row*1152 + w*32 + gt*16 + c] = (unsigned short)f2bf_cvt(hnew);
        }
      }
    }
    if (st < 7) __syncthreads();
  }
}

// ---------------- MLP1/MLP2 over (b,s) rows: sf -> enc part of combined ----------------
__global__ __launch_bounds__(256) void k_mlp12(
    const unsigned short* __restrict__ sf,    // [16384][96]
    const unsigned short* __restrict__ wgt,
    const float* __restrict__ b1, const float* __restrict__ b2,
    unsigned short* __restrict__ combined)
{
  __shared__ char smem[18432];
  unsigned short* hb = (unsigned short*)smem + (threadIdx.x >> 6) * 2176;  // [16][136]/wave
  float* b1s = (float*)(smem + 17408);
  float* b2s = b1s + 128;
  const unsigned short* w1b = wgt + 49152;
  const unsigned short* w2b = wgt + 61440;
  const int tid = threadIdx.x, w = tid >> 6, u = (tid >> 4) & 3, c = tid & 15;
  if (tid < 128){ b1s[tid] = b1[tid]; b2s[tid] = b2[tid]; }
  __syncthreads();
  const int rowb = blockIdx.x * 64 + w * 16;

  f32x4 acc[8];
#pragma unroll
  for (int nt=0; nt<8; ++nt) acc[nt] = (f32x4){0.f,0.f,0.f,0.f};
#pragma unroll
  for (int kc=0; kc<3; ++kc){
    short8 a = *(const short8*)&sf[(size_t)(rowb + c)*96 + kc*32 + u*8];
#pragma unroll
    for (int nt=0; nt<8; ++nt){
      short8 bb = *(const short8*)&w1b[(nt*16+c)*96 + kc*32 + u*8];
      acc[nt] = __builtin_amdgcn_mfma_f32_16x16x32_bf16(a, bb, acc[nt], 0,0,0);
    }
  }
#pragma unroll
  for (int nt=0; nt<8; ++nt){
    float bias = b1s[nt*16+c];
#pragma unroll
    for (int q=0; q<4; ++q){
      float v = acc[nt][q] + bias; v = v > 0.f ? v : 0.f;
      hb[(u*4+q)*136 + nt*16 + c] = (unsigned short)f2bf_cvt(v);
    }
  }
  f32x4 acc2[8];
#pragma unroll
  for (int nt=0; nt<8; ++nt) acc2[nt] = (f32x4){0.f,0.f,0.f,0.f};
#pragma unroll
  for (int kc=0; kc<4; ++kc){
    short8 a = *(short8*)&hb[c*136 + kc*32 + u*8];
#pragma unroll
    for (int nt=0; nt<8; ++nt){
      short8 bb = *(const short8*)&w2b[(nt*16+c)*128 + kc*32 + u*8];
      acc2[nt] = __builtin_amdgcn_mfma_f32_16x16x32_bf16(a, bb, acc2[nt], 0,0,0);
    }
  }
#pragma unroll
  for (int nt=0; nt<8; ++nt){
    float bias = b2s[nt*16+c];
#pragma unroll
    for (int q=0; q<4; ++q){
      float v = acc2[nt][q] + bias; v = v > 0.f ? v : 0.f;
      int r = rowb + u*4 + q;
      combined[(size_t)(r >> 3)*1152 + 128 + (r & 7)*128 + nt*16 + c] = (unsigned short)f2bf_cvt(v);
    }
  }
}

// ---------------- head v2: 128 blocks x 256 thr (4 waves) ----------------
__global__ __launch_bounds__(256) void k_head(
    const unsigned short* __restrict__ combined,
    const unsigned short* __restrict__ wgt,
    const float* __restrict__ bf1, const float* __restrict__ bf2, const float* __restrict__ bf3,
    const float* __restrict__ lng, const float* __restrict__ lnb,
    float* __restrict__ out)
{
  __shared__ char smem[15104];
  const int tid = threadIdx.x, w = tid >> 6, u = (tid >> 4) & 3, c = tid & 15;
  unsigned short* f1b = (unsigned short*)smem;                 // [16][264]
  unsigned short* f2b = (unsigned short*)(smem + 8448);        // [16][136]
  float* bf1s = (float*)(smem + 12800); float* bf2s = (float*)(smem + 13824);
  float* bf3s = (float*)(smem + 14336);
  float* lngs = (float*)(smem + 14592); float* lnbs = (float*)(smem + 14848);
  const unsigned short* wf1b = wgt + 77824;
  const unsigned short* wf2b = wgt + 372736;
  const unsigned short* wf3b = wgt + 405504;
  bf1s[tid] = bf1[tid];
  if (tid < 128) bf2s[tid] = bf2[tid];
  if (tid < 64){ bf3s[tid] = bf3[tid]; lngs[tid] = lng[tid]; lnbs[tid] = lnb[tid]; }
  __syncthreads();
  const int rowb = blockIdx.x * 16;

  f32x4 acc[4];
#pragma unroll
  for (int i=0; i<4; ++i) acc[i] = (f32x4){0.f,0.f,0.f,0.f};
#pragma unroll 4
  for (int kc=0; kc<36; ++kc){
    short8 a = *(const short8*)&combined[(size_t)(rowb + c)*1152 + kc*32 + u*8];
#pragma unroll
    for (int i=0; i<4; ++i){
      int nt = w*4 + i;
      short8 bb = *(const short8*)&wf1b[(size_t)(nt*16+c)*1152 + kc*32 + u*8];
      acc[i] = __builtin_amdgcn_mfma_f32_16x16x32_bf16(a, bb, acc[i], 0,0,0);
    }
  }
#pragma unroll
  for (int i=0; i<4; ++i){
    int nt = w*4 + i;
    float bias = bf1s[nt*16+c];
#pragma unroll
    for (int q=0; q<4; ++q){
      float v = acc[i][q] + bias; v = v > 0.f ? v : 0.f;
      f1b[(u*4+q)*264 + nt*16 + c] = (unsigned short)f2bf_cvt(v);
    }
  }
  __syncthreads();

  f32x4 acc2[2];
#pragma unroll
  for (int i=0; i<2; ++i) acc2[i] = (f32x4){0.f,0.f,0.f,0.f};
#pragma unroll
  for (int kc=0; kc<8; ++kc){
    short8 a = *(short8*)&f1b[c*264 + kc*32 + u*8];
#pragma unroll
    for (int i=0; i<2; ++i){
      int nt = w*2 + i;
      short8 bb = *(const short8*)&wf2b[(nt*16+c)*256 + kc*32 + u*8];
      acc2[i] = __builtin_amdgcn_mfma_f32_16x16x32_bf16(a, bb, acc2[i], 0,0,0);
    }
  }
#pragma unroll
  for (int i=0; i<2; ++i){
    int nt = w*2 + i;
    float bias = bf2s[nt*16+c];
#pragma unroll
    for (int q=0; q<4; ++q){
      float v = acc2[i][q] + bias; v = v > 0.f ? v : 0.f;
      f2b[(u*4+q)*136 + nt*16 + c] = (unsigned short)f2bf_cvt(v);
    }
  }
  __syncthreads();

  f32x4 acc3[4];
#pragma unroll
  for (int nt=0; nt<4; ++nt) acc3[nt] = (f32x4){0.f,0.f,0.f,0.f};
#pragma unroll
  for (int kc=0; kc<4; ++kc){
    short8 a = *(short8*)&f2b[c*136 + kc*32 + u*8];
#pragma unroll
    for (int nt=0; nt<4; ++nt){
      short8 bb = *(const short8*)&wf3b[(nt*16+c)*128 + kc*32 + u*8];
      acc3[nt] = __builtin_amdgcn_mfma_f32_16x16x32_bf16(a, bb, acc3[nt], 0,0,0);
    }
  }
  if (w == 0){
    float v[4][4];
#pragma unroll
    for (int nt=0; nt<4; ++nt){
      float bias = bf3s[nt*16+c];
#pragma unroll
      for (int q=0; q<4; ++q){
        float t = acc3[nt][q] + bias; v[nt][q] = t > 0.f ? t : 0.f;
      }
    }
#pragma unroll
    for (int q=0; q<4; ++q){
      float p = v[0][q] + v[1][q] + v[2][q] + v[3][q];
      p += __shfl_xor(p, 1); p += __shfl_xor(p, 2); p += __shfl_xor(p, 4); p += __shfl_xor(p, 8);
      float mu = p * 0.015625f;
      float d0 = v[0][q]-mu, d1 = v[1][q]-mu, d2 = v[2][q]-mu, d3 = v[3][q]-mu;
      float p2 = d0*d0 + d1*d1 + d2*d2 + d3*d3;
      p2 += __shfl_xor(p2, 1); p2 += __shfl_xor(p2, 2); p2 += __shfl_xor(p2, 4); p2 += __shfl_xor(p2, 8);
      float rstd = __builtin_amdgcn_rsqf(p2 * 0.015625f + 1e-5f);
      int row = rowb + u*4 + q;
#pragma unroll
      for (int nt=0; nt<4; ++nt){
        int col = nt*16 + c;
        out[(size_t)row*64 + col] = (v[nt][q] - mu) * rstd * lngs[col] + lnbs[col];
      }
    }
  }
}

extern "C" void kernel_launch(void* const* d_in, const int* in_sizes, int n_in,
                              void* d_out, int out_size, void* d_ws, size_t ws_size,
                              hipStream_t stream)
{
  const float* ttraj = (const float*)d_in[0];
  const float* ntraj = (const float*)d_in[1];
  const float* rang  = (const float*)d_in[2];
  const float* nmask = (const float*)d_in[3];
  const float* Wih_t = (const float*)d_in[4];
  const float* Whh_t = (const float*)d_in[5];
  const float* bih_t = (const float*)d_in[6];
  const float* bhh_t = (const float*)d_in[7];
  const float* Wih_n = (const float*)d_in[8];
  const float* Whh_n = (const float*)d_in[9];
  const float* bih_n = (const float*)d_in[10];
  const float* bhh_n = (const float*)d_in[11];
  const float* W1  = (const float*)d_in[12];
  const float* b1  = (const float*)d_in[13];
  const float* W2  = (const float*)d_in[14];
  const float* b2  = (const float*)d_in[15];
  const float* Wf1 = (const float*)d_in[16];
  const float* bf1 = (const float*)d_in[17];
  const float* Wf2 = (const float*)d_in[18];
  const float* bf2 = (const float*)d_in[19];
  const float* Wf3 = (const float*)d_in[20];
  const float* bf3 = (const float*)d_in[21];
  const float* lng = (const float*)d_in[22];
  const float* lnb = (const float*)d_in[23];

  char* ws = (char*)d_ws;
  unsigned short* combined = (unsigned short*)ws;                  // [2048][1152] bf16
  unsigned short* sf       = (unsigned short*)(ws + 5242880);      // [16384][96] bf16
  unsigned short* wgt      = (unsigned short*)(ws + 8388608);      // bf16 weights

  hipLaunchKernelGGL(k_prep, dim3(1664), dim3(256), 0, stream,
                     Whh_t, W1, W2, Wf1, Wf2, Wf3, Whh_n, wgt);
  hipLaunchKernelGGL(k_gru_n, dim3(1024), dim3(512), 0, stream,
                     ttraj, ntraj, rang, nmask, Wih_n, bih_n, bhh_n, wgt, sf);
  hipLaunchKernelGGL(k_gru_t, dim3(128), dim3(256), 0, stream,
                     ttraj, Wih_t, bih_t, bhh_t, wgt, combined);
  hipLaunchKernelGGL(k_mlp12, dim3(256), dim3(256), 0, stream, sf, wgt, b1, b2, combined);
  hipLaunchKernelGGL(k_head, dim3(128), dim3(256), 0, stream,
                     combined, wgt, bf1, bf2, bf3, lng, lnb, (float*)d_out);
}

// Round 9
// 135.054 us; speedup vs baseline: 1.2943x; 1.0008x over previous
//
#include <hip/hip_runtime.h>

typedef __attribute__((ext_vector_type(8))) short short8;
typedef __attribute__((ext_vector_type(4))) float f32x4;

#define SGC (-1.44269504088896341f)   /* -log2(e): sigmoid prescale */
#define THC ( 2.88539008177792681f)   /* 2*log2(e): tanh prescale   */

__device__ __forceinline__ unsigned short f2bf(float f){
  unsigned u = __float_as_uint(f);
  return (unsigned short)((u + 0x7fffu + ((u >> 16) & 1u)) >> 16);
}
__device__ __forceinline__ float bf2f(unsigned short b){
  return __uint_as_float(((unsigned)b) << 16);
}
// single f32 -> bf16 (RNE) in one VALU op; low 16 bits of result are valid
__device__ __forceinline__ unsigned f2bf_cvt(float f){
  unsigned r;
  asm("v_cvt_pk_bf16_f32 %0, %1, %1" : "=v"(r) : "v"(f));
  return r;
}
__device__ __forceinline__ unsigned f2bf_pk(float lo, float hi){
  unsigned r;
  asm("v_cvt_pk_bf16_f32 %0, %1, %2" : "=v"(r) : "v"(lo), "v"(hi));
  return r;
}

// ---------------- weight conversion: fp32 -> bf16 in ws ----------------
// wgt layout (u16 elems):
//   whhT_b [384*128]  @0        (PRESCALED: rows<256 *SGC, rows>=256 *THC)
//   W1b    [128*96]   @49152    (96 = 68 padded, zeros)
//   W2b    [128*128]  @61440
//   Wf1b   [256*1152] @77824
//   Wf2b   [128*256]  @372736
//   Wf3b   [64*128]   @405504
//   whhN_b [192*64]   @413696   (PRESCALED: rows<128 *SGC, rows>=128 *THC)
__global__ __launch_bounds__(256) void k_prep(
    const float* __restrict__ Whh_t, const float* __restrict__ W1,
    const float* __restrict__ W2,    const float* __restrict__ Wf1,
    const float* __restrict__ Wf2,   const float* __restrict__ Wf3,
    const float* __restrict__ Whh_n,
    unsigned short* __restrict__ wgt)
{
  int i = blockIdx.x * 256 + threadIdx.x;
  if (i < 49152){
    int g = i >> 7;
    float s = (g < 256) ? SGC : THC;
    wgt[i] = f2bf(Whh_t[i] * s); return;
  }
  i -= 49152;
  if (i < 12288){ int r = i / 96, c = i % 96;
    wgt[49152 + i] = (c < 68) ? f2bf(W1[r*68 + c]) : (unsigned short)0; return; }
  i -= 12288;
  if (i < 16384){ wgt[61440 + i] = f2bf(W2[i]); return; }
  i -= 16384;
  if (i < 294912){ wgt[77824 + i] = f2bf(Wf1[i]); return; }
  i -= 294912;
  if (i < 32768){ wgt[372736 + i] = f2bf(Wf2[i]); return; }
  i -= 32768;
  if (i < 8192){ wgt[405504 + i] = f2bf(Wf3[i]); return; }
  i -= 8192;
  if (i < 12288){
    int g = i >> 6;
    float s = (g < 128) ? SGC : THC;
    wgt[413696 + i] = f2bf(Whh_n[i] * s); return;
  }
}

// ---------------- neighbor GRU + sector pooling ----------------
// 2048 blocks x 256 threads; ONE batch per block.
// LDS 38912 B -> 4 blocks/CU (fits 163840 even with +1KB alloc rounding):
//   whh2 [12][2][64][8] 24576 | wx [12][16][8] 3072 |
//   hall 4x[16][72] 9216 | xpk [8][64] u32 packed-bf16 2048.
// Pooling scratch aliases xpk; positions re-read from L2-hot ntraj.
// x-proj + biases folded into MFMA (K=96 augmentation); x-tile B-frags
// hoisted to registers (BX[12], step-invariant).
// launch_bounds (256,4): VGPR cap 128 (need ~90; r6 spill was cap 84).
__global__ __launch_bounds__(256, 4) void k_gru_n(
    const float* __restrict__ ttraj, const float* __restrict__ ntraj,
    const float* __restrict__ rang,  const float* __restrict__ nmask,
    const float* __restrict__ Wih_n,
    const float* __restrict__ bih_n, const float* __restrict__ bhh_n,
    const unsigned short* __restrict__ wgt,
    unsigned short* __restrict__ sf)             // [16384][96] bf16
{
  __shared__ char smem[38912];
  const int tid = threadIdx.x;
  const int w = tid >> 6, u = (tid >> 4) & 3, c = tid & 15;
  const int b = blockIdx.x;
  const unsigned short* whhN_b = wgt + 413696;   // [192][64] prescaled

  unsigned short* whh2 = (unsigned short*)smem;                 // [12][2][64][8]
  unsigned short* wx   = whh2 + 12288;                          // [12][16][8]
  unsigned short* hall = (unsigned short*)(smem + 27648);       // 4 x [16][72]
  unsigned short* hb   = hall + w * 1152;
  unsigned* xpk = (unsigned*)(smem + 36864);                    // [8][64] u32
  float* pool   = (float*)(smem + 36864);                       // alias (512 f32)

  // stage hh weights lane-linear: whh2[nt][half][u*16+c][8]
  for (int i = tid; i < 1536; i += 256){
    int nt = i >> 7, rem = i & 127;
    int hf = rem >> 6, uu = (rem >> 4) & 3, cc = rem & 15;
    *(short8*)&whh2[nt*1024 + hf*512 + (uu*16+cc)*8] =
        *(const short8*)&whhN_b[(nt*16+cc)*64 + hf*32 + uu*8];
  }
  // stage x-tiles: rows 64,65,66 = W0*s, W1*s, bias*s (rest 0)
  if (tid < 192){
    int t = tid >> 4, cc = tid & 15;
    float s = (t < 8) ? SGC : THC;
    int g = (t < 4) ? (t*16 + cc) : (t < 8) ? (64 + (t-4)*16 + cc) : (128 + (t-8)*16 + cc);
    float bsum = (t < 8) ? (bih_n[g] + bhh_n[g]) : bih_n[g];
    unsigned short* p = &wx[t*128 + cc*8];
    *(short8*)p = (short8){0,0,0,0,0,0,0,0};
    p[0] = f2bf(Wih_n[g*2]   * s);
    p[1] = f2bf(Wih_n[g*2+1] * s);
    p[2] = f2bf(bsum * s);
  }
  // stage trajectories packed bf16: xpk[step][seq]
  {
    float4 v = ((const float4*)(ntraj + (size_t)b * 1024))[tid];
    int n = tid >> 2, p = (tid & 3) * 2;
    xpk[p*64 + n]       = f2bf_pk(v.x, v.y);
    xpk[(p+1)*64 + n]   = f2bf_pk(v.z, v.w);
  }
  __syncthreads();

  // hoist x-tile B fragments (step-invariant)
  short8 BX[12];
#pragma unroll
  for (int t = 0; t < 12; ++t) BX[t] = *(const short8*)&wx[t*128 + c*8];

  float bh_[4];
#pragma unroll
  for (int gt = 0; gt < 4; ++gt) bh_[gt] = bhh_n[128 + gt*16 + c] * THC;

  float hcur[4][4];
#pragma unroll
  for (int gt=0; gt<4; ++gt)
#pragma unroll
    for (int q=0; q<4; ++q) hcur[gt][q] = 0.0f;

  auto gates = [&](int gt, const f32x4& aR, const f32x4& aZ, const f32x4& aN, const f32x4& aX){
#pragma unroll
    for (int q = 0; q < 4; ++q){
      float r = __builtin_amdgcn_rcpf(1.0f + __builtin_amdgcn_exp2f(aR[q]));
      float z = __builtin_amdgcn_rcpf(1.0f + __builtin_amdgcn_exp2f(aZ[q]));
      float hn = aN[q] + bh_[gt];
      float pn = __builtin_fmaf(r, hn, aX[q]);
      float E = __builtin_amdgcn_exp2f(pn);
      float n = __builtin_fmaf(-2.0f, __builtin_amdgcn_rcpf(E + 1.0f), 1.0f);
      float hnew = __builtin_fmaf(z, hcur[gt][q] - n, n);
      hcur[gt][q] = hnew;
      hb[(u*4+q)*72 + gt*16 + c] = (unsigned short)f2bf_cvt(hnew);
    }
  };

  const int lane8 = (u*16 + c) * 8;
  const f32x4 zz = {0.f,0.f,0.f,0.f};

  for (int st = 0; st < 8; ++st){
    // augmented A chunk a2 = [x0, x1, 1.0, 0...] (u==0 lanes only)
    unsigned p01 = xpk[st*64 + w*16 + c];
    bool u0 = (u == 0);
    union { unsigned ui[4]; short8 s8; } a2u;
    a2u.ui[0] = u0 ? p01 : 0u;
    a2u.ui[1] = u0 ? 0x3F80u : 0u;   // bf16(1.0) in halfword 2
    a2u.ui[2] = 0u; a2u.ui[3] = 0u;
    short8 a2 = a2u.s8;

    if (st > 0){
      short8 a0 = *(short8*)&hb[c*72 + u*8];
      short8 a1 = *(short8*)&hb[c*72 + 32 + u*8];
#pragma unroll
      for (int gt = 0; gt < 4; ++gt){
        const unsigned short* pr = whh2 + gt*1024 + lane8;
        const unsigned short* pz = whh2 + (4+gt)*1024 + lane8;
        const unsigned short* pq = whh2 + (8+gt)*1024 + lane8;
        f32x4 aR = __builtin_amdgcn_mfma_f32_16x16x32_bf16(a0, *(const short8*)pr, zz, 0,0,0);
        aR = __builtin_amdgcn_mfma_f32_16x16x32_bf16(a1, *(const short8*)(pr+512), aR, 0,0,0);
        aR = __builtin_amdgcn_mfma_f32_16x16x32_bf16(a2, BX[gt], aR, 0,0,0);
        f32x4 aZ = __builtin_amdgcn_mfma_f32_16x16x32_bf16(a0, *(const short8*)pz, zz, 0,0,0);
        aZ = __builtin_amdgcn_mfma_f32_16x16x32_bf16(a1, *(const short8*)(pz+512), aZ, 0,0,0);
        aZ = __builtin_amdgcn_mfma_f32_16x16x32_bf16(a2, BX[4+gt], aZ, 0,0,0);
        f32x4 aN = __builtin_amdgcn_mfma_f32_16x16x32_bf16(a0, *(const short8*)pq, zz, 0,0,0);
        aN = __builtin_amdgcn_mfma_f32_16x16x32_bf16(a1, *(const short8*)(pq+512), aN, 0,0,0);
        f32x4 aX = __builtin_amdgcn_mfma_f32_16x16x32_bf16(a2, BX[8+gt], zz, 0,0,0);
        gates(gt, aR, aZ, aN, aX);
      }
    } else {
#pragma unroll
      for (int gt = 0; gt < 4; ++gt){
        f32x4 aR = __builtin_amdgcn_mfma_f32_16x16x32_bf16(a2, BX[gt], zz, 0,0,0);
        f32x4 aZ = __builtin_amdgcn_mfma_f32_16x16x32_bf16(a2, BX[4+gt], zz, 0,0,0);
        f32x4 aX = __builtin_amdgcn_mfma_f32_16x16x32_bf16(a2, BX[8+gt], zz, 0,0,0);
        gates(gt, aR, aZ, zz, aX);
      }
    }
  }
  __syncthreads();

  // ---- sector pooling (scratch aliases xpk; positions from L2-hot ntraj) ----
  // pool: dist@[0..63] vx@[64..127] vy@[128..191] wv@[192..255] sid@[256..319]
  //       cnt@[320+s] avgd@[328+s] avx@[336+s] avy@[344+s] winv@[352+s]
  if (tid < 64){
    int n = tid;
    const float* nb = ntraj + (size_t)b*1024 + n*16;   // this neighbor's [8][2]
    float px = nb[14], py = nb[15];
    float vx = px - nb[12], vy = py - nb[13];
    float m   = nmask[(size_t)b*64 + n];
    float ang = rang[(size_t)b*64 + n];
    float tx = ttraj[(size_t)b*16 + 14], ty = ttraj[(size_t)b*16 + 15];
    float dx = px - tx, dy = py - ty;
    float dist = __builtin_amdgcn_sqrtf(dx*dx + dy*dy);
    int sid = (int)(ang / 0.78539816339744830962f);
    sid = sid < 0 ? 0 : (sid > 7 ? 7 : sid);
    bool valid = m > 0.0f;
    float wv = valid ? __builtin_amdgcn_exp2f(dist * -0.14426950408889634f) : 0.0f;
    pool[n]       = valid ? dist : 0.0f;
    pool[64 + n]  = valid ? vx   : 0.0f;
    pool[128 + n] = valid ? vy   : 0.0f;
    pool[192 + n] = wv;
    pool[256 + n] = valid ? (float)sid : -1.0f;
  }
  __syncthreads();
  if (tid < 8){
    int s = tid;
    float cnt=0.f, sd=0.f, sx=0.f, sy=0.f, sw=0.f;
    for (int n=0; n<64; ++n){
      if (pool[256+n] == (float)s){
        cnt += 1.f; sd += pool[n]; sx += pool[64+n]; sy += pool[128+n]; sw += pool[192+n];
      }
    }
    float inv = (cnt > 0.f) ? __builtin_amdgcn_rcpf(cnt) : 0.f;
    pool[320 + s] = cnt;
    pool[328 + s] = sd * inv;
    pool[336 + s] = sx * inv;
    pool[344 + s] = sy * inv;
    pool[352 + s] = __builtin_amdgcn_rcpf(sw + 1e-8f);
  }
  __syncthreads();
#pragma unroll
  for (int rep = 0; rep < 2; ++rep){
    int p = tid + rep*256;
    int s = p >> 6, h = p & 63;
    float fs = (float)s;
    float a = 0.f;
    for (int n = 0; n < 64; ++n){
      float wmv = (pool[256+n] == fs) ? pool[192+n] : 0.f;
      float nf  = bf2f(hall[(n>>4)*1152 + (n&15)*72 + h]);
      a += wmv * nf;
    }
    sf[((size_t)b*8 + s)*96 + 4 + h] = (unsigned short)f2bf_cvt(a * pool[352+s]);
  }
  if (tid < 32){
    int s = tid >> 2, cc = tid & 3;
    sf[((size_t)b*8 + s)*96 + cc] = (unsigned short)f2bf_cvt(pool[320 + cc*8 + s]);
  }
  if (tid < 224){
    int s = tid / 28, cc = 68 + tid % 28;
    sf[((size_t)b*8 + s)*96 + cc] = 0;
  }
}

// ---------------- target GRU: 128 blocks x 256 thr (4 waves) ----------------
// Wave w owns hidden slice [w*32, w*32+32); B-frags register-resident.
// whhT_b is PRESCALED (r,z rows *SGC; n rows *THC).
__global__ __launch_bounds__(256) void k_gru_t(
    const float* __restrict__ ttraj,
    const float* __restrict__ Wih_t, const float* __restrict__ bih_t, const float* __restrict__ bhh_t,
    const unsigned short* __restrict__ wgt,      // whhT_b [384][128] @0
    unsigned short* __restrict__ combined)       // [2048][1152] bf16
{
  __shared__ char smem[9728];
  const int tid = threadIdx.x, w = tid >> 6, u = (tid >> 4) & 3, c = tid & 15;
  unsigned short* hb0 = (unsigned short*)smem;             // [16][136]
  unsigned short* hb1 = (unsigned short*)(smem + 4352);    // [16][136]
  float* xs = (float*)(smem + 8704);                       // [16][16]

  xs[tid] = ttraj[(size_t)blockIdx.x*256 + tid];

  int ntg[6];
  ntg[0] = 2*w; ntg[1] = 2*w+1;
  ntg[2] = 8+2*w; ntg[3] = 9+2*w;
  ntg[4] = 16+2*w; ntg[5] = 17+2*w;

  short8 Bf[6][4];
#pragma unroll
  for (int lt2 = 0; lt2 < 6; ++lt2){
    const unsigned short* wp = wgt + (ntg[lt2]*16 + c)*128 + u*8;
#pragma unroll
    for (int kk = 0; kk < 4; ++kk)
      Bf[lt2][kk] = *(const short8*)(wp + kk*32);
  }

  float Wr0[2],Wr1[2],BR[2],Wz0[2],Wz1[2],BZ[2],Wn0[2],Wn1[2],BI[2],BH[2];
#pragma unroll
  for (int gt = 0; gt < 2; ++gt){
    int g = w*32 + gt*16 + c;
    Wr0[gt]=Wih_t[g*2]*SGC;        Wr1[gt]=Wih_t[g*2+1]*SGC;        BR[gt]=(bih_t[g]+bhh_t[g])*SGC;
    Wz0[gt]=Wih_t[(128+g)*2]*SGC;  Wz1[gt]=Wih_t[(128+g)*2+1]*SGC;  BZ[gt]=(bih_t[128+g]+bhh_t[128+g])*SGC;
    Wn0[gt]=Wih_t[(256+g)*2]*THC;  Wn1[gt]=Wih_t[(256+g)*2+1]*THC;  BI[gt]=bih_t[256+g]*THC; BH[gt]=bhh_t[256+g]*THC;
  }
  float hcur[2][4];
#pragma unroll
  for (int gt=0; gt<2; ++gt)
#pragma unroll
    for (int q=0; q<4; ++q) hcur[gt][q] = 0.0f;
  __syncthreads();

  for (int st = 0; st < 8; ++st){
    unsigned short* rbuf = (st & 1) ? hb0 : hb1;
    unsigned short* wbuf = (st & 1) ? hb1 : hb0;
    f32x4 acc[6];
    if (st > 0){
      short8 a0 = *(short8*)&rbuf[c*136 + u*8];
      short8 a1 = *(short8*)&rbuf[c*136 + 32 + u*8];
      short8 a2 = *(short8*)&rbuf[c*136 + 64 + u*8];
      short8 a3 = *(short8*)&rbuf[c*136 + 96 + u*8];
#pragma unroll
      for (int lt2 = 0; lt2 < 6; ++lt2){
        f32x4 t = {0.f,0.f,0.f,0.f};
        t = __builtin_amdgcn_mfma_f32_16x16x32_bf16(a0, Bf[lt2][0], t, 0,0,0);
        t = __builtin_amdgcn_mfma_f32_16x16x32_bf16(a1, Bf[lt2][1], t, 0,0,0);
        t = __builtin_amdgcn_mfma_f32_16x16x32_bf16(a2, Bf[lt2][2], t, 0,0,0);
        acc[lt2] = __builtin_amdgcn_mfma_f32_16x16x32_bf16(a3, Bf[lt2][3], t, 0,0,0);
      }
    } else {
#pragma unroll
      for (int lt2 = 0; lt2 < 6; ++lt2) acc[lt2] = (f32x4){0.f,0.f,0.f,0.f};
    }
#pragma unroll
    for (int gt = 0; gt < 2; ++gt){
#pragma unroll
      for (int q = 0; q < 4; ++q){
        int sq = u*4 + q;
        float x0 = xs[sq*16 + st*2], x1 = xs[sq*16 + st*2 + 1];
        float rp = __builtin_fmaf(Wr0[gt], x0, __builtin_fmaf(Wr1[gt], x1, acc[gt][q] + BR[gt]));
        float zp = __builtin_fmaf(Wz0[gt], x0, __builtin_fmaf(Wz1[gt], x1, acc[2+gt][q] + BZ[gt]));
        float r = __builtin_amdgcn_rcpf(1.0f + __builtin_amdgcn_exp2f(rp));
        float z = __builtin_amdgcn_rcpf(1.0f + __builtin_amdgcn_exp2f(zp));
        float hnv = acc[4+gt][q] + BH[gt];
        float pn = __builtin_fmaf(Wn0[gt], x0, __builtin_fmaf(Wn1[gt], x1, __builtin_fmaf(r, hnv, BI[gt])));
        float E = __builtin_amdgcn_exp2f(pn);
        float n = __builtin_fmaf(-2.0f, __builtin_amdgcn_rcpf(E + 1.0f), 1.0f);
        float hnew = __builtin_fmaf(z, hcur[gt][q] - n, n);
        hcur[gt][q] = hnew;
        if (st < 7){
          wbuf[sq*136 + w*32 + gt*16 + c] = (unsigned short)f2bf_cvt(hnew);
        } else {
          int row = blockIdx.x*16 + sq;
          combined[(size_t)row*1152 + w*32 + gt*16 + c] = (unsigned short)f2bf_cvt(hnew);
        }
      }
    }
    if (st < 7) __syncthreads();
  }
}

// ---------------- MLP1/MLP2 over (b,s) rows: sf -> enc part of combined ----------------
__global__ __launch_bounds__(256) void k_mlp12(
    const unsigned short* __restrict__ sf,    // [16384][96]
    const unsigned short* __restrict__ wgt,
    const float* __restrict__ b1, const float* __restrict__ b2,
    unsigned short* __restrict__ combined)
{
  __shared__ char smem[18432];
  unsigned short* hb = (unsigned short*)smem + (threadIdx.x >> 6) * 2176;  // [16][136]/wave
  float* b1s = (float*)(smem + 17408);
  float* b2s = b1s + 128;
  const unsigned short* w1b = wgt + 49152;
  const unsigned short* w2b = wgt + 61440;
  const int tid = threadIdx.x, w = tid >> 6, u = (tid >> 4) & 3, c = tid & 15;
  if (tid < 128){ b1s[tid] = b1[tid]; b2s[tid] = b2[tid]; }
  __syncthreads();
  const int rowb = blockIdx.x * 64 + w * 16;

  f32x4 acc[8];
#pragma unroll
  for (int nt=0; nt<8; ++nt) acc[nt] = (f32x4){0.f,0.f,0.f,0.f};
#pragma unroll
  for (int kc=0; kc<3; ++kc){
    short8 a = *(const short8*)&sf[(size_t)(rowb + c)*96 + kc*32 + u*8];
#pragma unroll
    for (int nt=0; nt<8; ++nt){
      short8 bb = *(const short8*)&w1b[(nt*16+c)*96 + kc*32 + u*8];
      acc[nt] = __builtin_amdgcn_mfma_f32_16x16x32_bf16(a, bb, acc[nt], 0,0,0);
    }
  }
#pragma unroll
  for (int nt=0; nt<8; ++nt){
    float bias = b1s[nt*16+c];
#pragma unroll
    for (int q=0; q<4; ++q){
      float v = acc[nt][q] + bias; v = v > 0.f ? v : 0.f;
      hb[(u*4+q)*136 + nt*16 + c] = (unsigned short)f2bf_cvt(v);
    }
  }
  f32x4 acc2[8];
#pragma unroll
  for (int nt=0; nt<8; ++nt) acc2[nt] = (f32x4){0.f,0.f,0.f,0.f};
#pragma unroll
  for (int kc=0; kc<4; ++kc){
    short8 a = *(short8*)&hb[c*136 + kc*32 + u*8];
#pragma unroll
    for (int nt=0; nt<8; ++nt){
      short8 bb = *(const short8*)&w2b[(nt*16+c)*128 + kc*32 + u*8];
      acc2[nt] = __builtin_amdgcn_mfma_f32_16x16x32_bf16(a, bb, acc2[nt], 0,0,0);
    }
  }
#pragma unroll
  for (int nt=0; nt<8; ++nt){
    float bias = b2s[nt*16+c];
#pragma unroll
    for (int q=0; q<4; ++q){
      float v = acc2[nt][q] + bias; v = v > 0.f ? v : 0.f;
      int r = rowb + u*4 + q;
      combined[(size_t)(r >> 3)*1152 + 128 + (r & 7)*128 + nt*16 + c] = (unsigned short)f2bf_cvt(v);
    }
  }
}

// ---------------- head v2: 128 blocks x 256 thr (4 waves) ----------------
__global__ __launch_bounds__(256) void k_head(
    const unsigned short* __restrict__ combined,
    const unsigned short* __restrict__ wgt,
    const float* __restrict__ bf1, const float* __restrict__ bf2, const float* __restrict__ bf3,
    const float* __restrict__ lng, const float* __restrict__ lnb,
    float* __restrict__ out)
{
  __shared__ char smem[15104];
  const int tid = threadIdx.x, w = tid >> 6, u = (tid >> 4) & 3, c = tid & 15;
  unsigned short* f1b = (unsigned short*)smem;                 // [16][264]
  unsigned short* f2b = (unsigned short*)(smem + 8448);        // [16][136]
  float* bf1s = (float*)(smem + 12800); float* bf2s = (float*)(smem + 13824);
  float* bf3s = (float*)(smem + 14336);
  float* lngs = (float*)(smem + 14592); float* lnbs = (float*)(smem + 14848);
  const unsigned short* wf1b = wgt + 77824;
  const unsigned short* wf2b = wgt + 372736;
  const unsigned short* wf3b = wgt + 405504;
  bf1s[tid] = bf1[tid];
  if (tid < 128) bf2s[tid] = bf2[tid];
  if (tid < 64){ bf3s[tid] = bf3[tid]; lngs[tid] = lng[tid]; lnbs[tid] = lnb[tid]; }
  __syncthreads();
  const int rowb = blockIdx.x * 16;

  f32x4 acc[4];
#pragma unroll
  for (int i=0; i<4; ++i) acc[i] = (f32x4){0.f,0.f,0.f,0.f};
#pragma unroll 4
  for (int kc=0; kc<36; ++kc){
    short8 a = *(const short8*)&combined[(size_t)(rowb + c)*1152 + kc*32 + u*8];
#pragma unroll
    for (int i=0; i<4; ++i){
      int nt = w*4 + i;
      short8 bb = *(const short8*)&wf1b[(size_t)(nt*16+c)*1152 + kc*32 + u*8];
      acc[i] = __builtin_amdgcn_mfma_f32_16x16x32_bf16(a, bb, acc[i], 0,0,0);
    }
  }
#pragma unroll
  for (int i=0; i<4; ++i){
    int nt = w*4 + i;
    float bias = bf1s[nt*16+c];
#pragma unroll
    for (int q=0; q<4; ++q){
      float v = acc[i][q] + bias; v = v > 0.f ? v : 0.f;
      f1b[(u*4+q)*264 + nt*16 + c] = (unsigned short)f2bf_cvt(v);
    }
  }
  __syncthreads();

  f32x4 acc2[2];
#pragma unroll
  for (int i=0; i<2; ++i) acc2[i] = (f32x4){0.f,0.f,0.f,0.f};
#pragma unroll
  for (int kc=0; kc<8; ++kc){
    short8 a = *(short8*)&f1b[c*264 + kc*32 + u*8];
#pragma unroll
    for (int i=0; i<2; ++i){
      int nt = w*2 + i;
      short8 bb = *(const short8*)&wf2b[(nt*16+c)*256 + kc*32 + u*8];
      acc2[i] = __builtin_amdgcn_mfma_f32_16x16x32_bf16(a, bb, acc2[i], 0,0,0);
    }
  }
#pragma unroll
  for (int i=0; i<2; ++i){
    int nt = w*2 + i;
    float bias = bf2s[nt*16+c];
#pragma unroll
    for (int q=0; q<4; ++q){
      float v = acc2[i][q] + bias; v = v > 0.f ? v : 0.f;
      f2b[(u*4+q)*136 + nt*16 + c] = (unsigned short)f2bf_cvt(v);
    }
  }
  __syncthreads();

  f32x4 acc3[4];
#pragma unroll
  for (int nt=0; nt<4; ++nt) acc3[nt] = (f32x4){0.f,0.f,0.f,0.f};
#pragma unroll
  for (int kc=0; kc<4; ++kc){
    short8 a = *(short8*)&f2b[c*136 + kc*32 + u*8];
#pragma unroll
    for (int nt=0; nt<4; ++nt){
      short8 bb = *(const short8*)&wf3b[(nt*16+c)*128 + kc*32 + u*8];
      acc3[nt] = __builtin_amdgcn_mfma_f32_16x16x32_bf16(a, bb, acc3[nt], 0,0,0);
    }
  }
  if (w == 0){
    float v[4][4];
#pragma unroll
    for (int nt=0; nt<4; ++nt){
      float bias = bf3s[nt*16+c];
#pragma unroll
      for (int q=0; q<4; ++q){
        float t = acc3[nt][q] + bias; v[nt][q] = t > 0.f ? t : 0.f;
      }
    }
#pragma unroll
    for (int q=0; q<4; ++q){
      float p = v[0][q] + v[1][q] + v[2][q] + v[3][q];
      p += __shfl_xor(p, 1); p += __shfl_xor(p, 2); p += __shfl_xor(p, 4); p += __shfl_xor(p, 8);
      float mu = p * 0.015625f;
      float d0 = v[0][q]-mu, d1 = v[1][q]-mu, d2 = v[2][q]-mu, d3 = v[3][q]-mu;
      float p2 = d0*d0 + d1*d1 + d2*d2 + d3*d3;
      p2 += __shfl_xor(p2, 1); p2 += __shfl_xor(p2, 2); p2 += __shfl_xor(p2, 4); p2 += __shfl_xor(p2, 8);
      float rstd = __builtin_amdgcn_rsqf(p2 * 0.015625f + 1e-5f);
      int row = rowb + u*4 + q;
#pragma unroll
      for (int nt=0; nt<4; ++nt){
        int col = nt*16 + c;
        out[(size_t)row*64 + col] = (v[nt][q] - mu) * rstd * lngs[col] + lnbs[col];
      }
    }
  }
}

extern "C" void kernel_launch(void* const* d_in, const int* in_sizes, int n_in,
                              void* d_out, int out_size, void* d_ws, size_t ws_size,
                              hipStream_t stream)
{
  const float* ttraj = (const float*)d_in[0];
  const float* ntraj = (const float*)d_in[1];
  const float* rang  = (const float*)d_in[2];
  const float* nmask = (const float*)d_in[3];
  const float* Wih_t = (const float*)d_in[4];
  const float* Whh_t = (const float*)d_in[5];
  const float* bih_t = (const float*)d_in[6];
  const float* bhh_t = (const float*)d_in[7];
  const float* Wih_n = (const float*)d_in[8];
  const float* Whh_n = (const float*)d_in[9];
  const float* bih_n = (const float*)d_in[10];
  const float* bhh_n = (const float*)d_in[11];
  const float* W1  = (const float*)d_in[12];
  const float* b1  = (const float*)d_in[13];
  const float* W2  = (const float*)d_in[14];
  const float* b2  = (const float*)d_in[15];
  const float* Wf1 = (const float*)d_in[16];
  const float* bf1 = (const float*)d_in[17];
  const float* Wf2 = (const float*)d_in[18];
  const float* bf2 = (const float*)d_in[19];
  const float* Wf3 = (const float*)d_in[20];
  const float* bf3 = (const float*)d_in[21];
  const float* lng = (const float*)d_in[22];
  const float* lnb = (const float*)d_in[23];

  char* ws = (char*)d_ws;
  unsigned short* combined = (unsigned short*)ws;                  // [2048][1152] bf16
  unsigned short* sf       = (unsigned short*)(ws + 5242880);      // [16384][96] bf16
  unsigned short* wgt      = (unsigned short*)(ws + 8388608);      // bf16 weights

  hipLaunchKernelGGL(k_prep, dim3(1664), dim3(256), 0, stream,
                     Whh_t, W1, W2, Wf1, Wf2, Wf3, Whh_n, wgt);
  hipLaunchKernelGGL(k_gru_n, dim3(2048), dim3(256), 0, stream,
                     ttraj, ntraj, rang, nmask, Wih_n, bih_n, bhh_n, wgt, sf);
  hipLaunchKernelGGL(k_gru_t, dim3(128), dim3(256), 0, stream,
                     ttraj, Wih_t, bih_t, bhh_t, wgt, combined);
  hipLaunchKernelGGL(k_mlp12, dim3(256), dim3(256), 0, stream, sf, wgt, b1, b2, combined);
  hipLaunchKernelGGL(k_head, dim3(128), dim3(256), 0, stream,
                     combined, wgt, bf1, bf2, bf3, lng, lnb, (float*)d_out);
}